// Round 10
// baseline (4154.341 us; speedup 1.0000x reference)
//
#include <hip/hip_runtime.h>
#include <hip/hip_bf16.h>
#include <math.h>

#define NN 20000
#define NE 256000
#define NODE_DIM_ 128
#define EDGE_DIM_ 8
#define HID 64
#define HEADS 4
#define NLAYERS 3
#define NCLASSES 3
#define NGRAPHS 64
#define HC 256  // HEADS*HID
#define NPB 8   // nodes per block in qkv

__device__ __forceinline__ int clampi(int x, int lo, int hi) { return min(max(x, lo), hi); }

// ---------------- diagnostics ----------------
__global__ void gt_write_const(float* out, int n, float val) {
    int i = blockIdx.x * blockDim.x + threadIdx.x;
    if (i < n) out[i] = val;
}

// Silent when healthy; encodes diagnostics into out when the pipeline is degenerate.
__global__ void gt_probe(const float* __restrict__ h, const float* __restrict__ lng,
                         float* out) {
    if (blockIdx.x != 0 || threadIdx.x != 0) return;
    float hbar = 0.f;
    for (int c = 0; c < HID; ++c) hbar += h[c];  // node 0 final h (relu'd)
    hbar *= (1.f / HID);
    float lng0 = lng[0];
    bool lngOK = fabsf(lng0 - 1.f) < 0.01f;
    bool hOK = (hbar >= 0.03f) && (hbar <= 3.f);
    if (lngOK && hOK) return;
    float v = 1000.f * fminf(fabsf(lng0), 3.f) + 100.f * fminf(fabsf(hbar), 5.f);
    for (int i = 0; i < NGRAPHS * NCLASSES; ++i) out[i] = 20.f + v;
}

// ---------------- utility ----------------
__global__ void gt_zero_i32(int* p, int n) {
    int i = blockIdx.x * blockDim.x + threadIdx.x;
    if (i < n) p[i] = 0;
}

// ---------------- h = x @ node_W + node_b  (4 nodes/block) ----------------
__global__ void gt_node_proj(const float* __restrict__ x, const float* __restrict__ W,
                             const float* __restrict__ b, float* __restrict__ h) {
    int t = threadIdx.x;            // 0..255
    int n = blockIdx.x * 4 + (t >> 6);
    int c = t & 63;
    __shared__ float xr[4][NODE_DIM_];
    for (int i = t; i < 4 * NODE_DIM_; i += 256) {
        int nn = blockIdx.x * 4 + i / NODE_DIM_;
        xr[i / NODE_DIM_][i % NODE_DIM_] = (nn < NN) ? x[(size_t)nn * NODE_DIM_ + i % NODE_DIM_] : 0.f;
    }
    __syncthreads();
    if (n >= NN) return;
    float acc = 0.f;
#pragma unroll 8
    for (int j = 0; j < NODE_DIM_; ++j) acc += xr[t >> 6][j] * W[j * HID + c];
    h[(size_t)n * HID + c] = acc + b[c];
}

// ---------------- e_feat = relu(ea@W1+b1)@W2+b2  (4 edges/block) ----------------
__global__ void gt_edge_mlp(const float* __restrict__ ea, const float* __restrict__ W1,
                            const float* __restrict__ b1, const float* __restrict__ W2,
                            const float* __restrict__ b2, float* __restrict__ ef) {
    int t = threadIdx.x;
    int sub = t >> 6, c = t & 63;
    int e = blockIdx.x * 4 + sub;
    __shared__ float a[4][EDGE_DIM_];
    __shared__ float t1[4][HID];
    for (int i = t; i < 4 * EDGE_DIM_; i += 256) {
        int eid = blockIdx.x * 4 + i / EDGE_DIM_;
        a[i / EDGE_DIM_][i % EDGE_DIM_] = (eid < NE) ? ea[(size_t)eid * EDGE_DIM_ + i % EDGE_DIM_] : 0.f;
    }
    __syncthreads();
    float acc = 0.f;
#pragma unroll
    for (int j = 0; j < EDGE_DIM_; ++j) acc += a[sub][j] * W1[j * HID + c];
    t1[sub][c] = fmaxf(acc + b1[c], 0.f);
    __syncthreads();
    if (e >= NE) return;
    float acc2 = 0.f;
#pragma unroll 8
    for (int j = 0; j < HID; ++j) acc2 += t1[sub][j] * W2[j * HID + c];
    ef[(size_t)e * HID + c] = acc2 + b2[c];
}

// ---------------- CSR build over dst ----------------
__global__ void gt_count_dst(const int* __restrict__ ei, int* cnt) {
    int e = blockIdx.x * blockDim.x + threadIdx.x;
    if (e < NE) {
        int d = clampi(ei[NE + e], 0, NN - 1);
        atomicAdd(&cnt[d], 1);
    }
}

__global__ void gt_scan_csr(const int* __restrict__ cnt, int* __restrict__ rp, int* __restrict__ cur) {
    __shared__ int part[256];
    int tid = threadIdx.x;
    const int CH = (NN + 255) / 256;  // 79
    int s0 = tid * CH, s1 = min(s0 + CH, NN);
    int s = 0;
    for (int i = s0; i < s1; ++i) s += cnt[i];
    part[tid] = s;
    __syncthreads();
    for (int off = 1; off < 256; off <<= 1) {
        int vv = (tid >= off) ? part[tid - off] : 0;
        __syncthreads();
        if (tid >= off) part[tid] += vv;
        __syncthreads();
    }
    int base = (tid == 0) ? 0 : part[tid - 1];
    for (int i = s0; i < s1; ++i) {
        rp[i] = base;
        cur[i] = base;
        base += cnt[i];
    }
    if (tid == 255) rp[NN] = part[255];
}

__global__ void gt_fill_csr(const int* __restrict__ ei, int* cur, int* csr) {
    int e = blockIdx.x * blockDim.x + threadIdx.x;
    if (e < NE) {
        int d = clampi(ei[NE + e], 0, NN - 1);
        int pos = atomicAdd(&cur[d], 1);
        if (pos >= 0 && pos < NE) csr[pos] = e;
    }
}

// ---------------- q,k,v projections (8 nodes/block) ----------------
__global__ void gt_qkv(const float* __restrict__ h, const float* __restrict__ Wq,
                       const float* __restrict__ bq, const float* __restrict__ Wk,
                       const float* __restrict__ bk, const float* __restrict__ Wv,
                       const float* __restrict__ bv,
                       float* __restrict__ q, float* __restrict__ k, float* __restrict__ v) {
    int t = threadIdx.x;  // 0..255
    int n0 = blockIdx.x * NPB;
    __shared__ float hs[NPB][HID];
    for (int i = t; i < NPB * HID; i += 256) {
        int nn = n0 + i / HID;
        hs[i / HID][i % HID] = (nn < NN) ? h[(size_t)nn * HID + i % HID] : 0.f;
    }
    __syncthreads();
    float aq[NPB], ak[NPB], av[NPB];
#pragma unroll
    for (int i = 0; i < NPB; ++i) { aq[i] = 0.f; ak[i] = 0.f; av[i] = 0.f; }
    for (int j = 0; j < HID; ++j) {
        float wq = Wq[j * HC + t];
        float wk = Wk[j * HC + t];
        float wv = Wv[j * HC + t];
#pragma unroll
        for (int i = 0; i < NPB; ++i) {
            aq[i] += hs[i][j] * wq;
            ak[i] += hs[i][j] * wk;
            av[i] += hs[i][j] * wv;
        }
    }
    float bqv = bq[t], bkv = bk[t], bvv = bv[t];
    for (int i = 0; i < NPB; ++i) {
        int nn = n0 + i;
        if (nn < NN) {
            q[(size_t)nn * HC + t] = aq[i] + bqv;
            k[(size_t)nn * HC + t] = ak[i] + bkv;
            v[(size_t)nn * HC + t] = av[i] + bvv;
        }
    }
}

// ---------------- DIRECT alpha: ee computed on the fly ----------------
__global__ void gt_alpha_direct(const float* __restrict__ q, const float* __restrict__ k,
                                const float* __restrict__ ef, const float* __restrict__ We,
                                const int* __restrict__ ei, float* __restrict__ alpha) {
    int e = blockIdx.x;
    int t = threadIdx.x;  // 256 = 4 waves = 4 heads
    __shared__ float sEf[HID];
    if (t < HID) sEf[t] = ef[(size_t)e * HID + t];
    __syncthreads();
    int src = clampi(ei[e], 0, NN - 1);
    int dst = clampi(ei[NE + e], 0, NN - 1);
    float eec = 0.f;
#pragma unroll 8
    for (int j = 0; j < HID; ++j) eec += sEf[j] * We[(size_t)j * HC + t];
    float p = q[(size_t)dst * HC + t] * (k[(size_t)src * HC + t] + eec);
#pragma unroll
    for (int s = 32; s > 0; s >>= 1) p += __shfl_down(p, s, 64);
    if ((t & 63) == 0) alpha[e * HEADS + (t >> 6)] = p * 0.125f;  // 1/sqrt(64)
}

// ---------------- segment softmax over in-edges ----------------
__global__ void gt_seg_softmax(const int* __restrict__ rp, const int* __restrict__ csr,
                               float* __restrict__ alpha) {
    int idx = blockIdx.x * blockDim.x + threadIdx.x;
    if (idx >= NN * HEADS) return;
    int n = idx / HEADS, hh = idx % HEADS;
    int s0 = clampi(rp[n], 0, NE), s1 = clampi(rp[n + 1], s0, NE);
    if (s0 == s1) return;
    float m = -1e30f;
    for (int i = s0; i < s1; ++i) m = fmaxf(m, alpha[clampi(csr[i], 0, NE - 1) * HEADS + hh]);
    float den = 0.f;
    for (int i = s0; i < s1; ++i) den += __expf(alpha[clampi(csr[i], 0, NE - 1) * HEADS + hh] - m);
    float inv = 1.f / den;
    for (int i = s0; i < s1; ++i) {
        int e = clampi(csr[i], 0, NE - 1);
        alpha[e * HEADS + hh] = __expf(alpha[e * HEADS + hh] - m) * inv;
    }
}

// ---------------- DIRECT aggregate + mean heads + skip + LN + relu ----------------
__global__ void gt_agg_direct(const float* __restrict__ v, const float* __restrict__ ef,
                              const float* __restrict__ We, const float* __restrict__ alpha,
                              const int* __restrict__ ei, const int* __restrict__ rp,
                              const int* __restrict__ csr, const float* __restrict__ Wskip,
                              const float* __restrict__ bskip, const float* __restrict__ lng,
                              const float* __restrict__ lnb, float* __restrict__ h) {
    int n = blockIdx.x;
    int t = threadIdx.x;  // 0..255
    int h2 = t >> 6;
    __shared__ float sEf[HID];
    __shared__ float sC[HC];
    __shared__ float res[HID];
    if (t < HID) res[t] = h[(size_t)n * HID + t];
    int s0 = clampi(rp[n], 0, NE), s1 = clampi(rp[n + 1], s0, NE);
    float acc = 0.f;
    for (int i = s0; i < s1; ++i) {
        int e = clampi(csr[i], 0, NE - 1);
        __syncthreads();
        if (t < HID) sEf[t] = ef[(size_t)e * HID + t];
        __syncthreads();
        float eec = 0.f;
#pragma unroll 8
        for (int j = 0; j < HID; ++j) eec += sEf[j] * We[(size_t)j * HC + t];
        int src = clampi(ei[e], 0, NN - 1);
        float a = alpha[e * HEADS + h2];
        acc += a * (v[(size_t)src * HC + t] + eec);
    }
    sC[t] = acc;
    __syncthreads();
    if (t < HID) {
        float conv = 0.25f * (sC[t] + sC[HID + t] + sC[2 * HID + t] + sC[3 * HID + t]);
        float sk = bskip[t];
#pragma unroll 8
        for (int j = 0; j < HID; ++j) sk += res[j] * Wskip[j * HID + t];
        float y = conv + sk + res[t];
        float m = y;
#pragma unroll
        for (int s = 32; s > 0; s >>= 1) m += __shfl_xor(m, s, 64);
        m *= (1.f / HID);
        float d = y - m;
        float vv = d * d;
#pragma unroll
        for (int s = 32; s > 0; s >>= 1) vv += __shfl_xor(vv, s, 64);
        vv *= (1.f / HID);
        float o = d * rsqrtf(vv + 1e-5f) * lng[t] + lnb[t];
        h[(size_t)n * HID + t] = fmaxf(o, 0.f);
    }
}

// ---------------- pool (true count) + classifier ----------------
__global__ void gt_pool_classify(const float* __restrict__ h, const int* __restrict__ batch,
                                 const float* __restrict__ W, const float* __restrict__ b,
                                 float* __restrict__ out) {
    int g = blockIdx.x;   // 0..63
    int c = threadIdx.x;  // 0..63
    __shared__ float pooled[HID];
    __shared__ float lg[4];
    __shared__ int bounds[2];
    if (c < 2) {
        int target = g + c;
        int lo = 0, hi = NN;
        while (lo < hi) {
            int mid = (lo + hi) >> 1;
            if (batch[mid] < target) lo = mid + 1; else hi = mid;
        }
        bounds[c] = lo;
    }
    __syncthreads();
    int n0 = bounds[0], n1 = bounds[1];
    float s = 0.f;
    for (int n = n0; n < n1; ++n) s += h[(size_t)n * HID + c];
    float divf = fmaxf((float)(n1 - n0), 1.f);
    pooled[c] = s / divf;
    __syncthreads();
    if (c < NCLASSES) {
        float acc = 0.f;
        for (int j = 0; j < HID; ++j) acc += pooled[j] * W[j * NCLASSES + c];
        lg[c] = acc + b[c];
    }
    __syncthreads();
    if (c == 0) {
        float m = fmaxf(lg[0], fmaxf(lg[1], lg[2]));
        float ssum = 0.f;
        for (int cc = 0; cc < NCLASSES; ++cc) ssum += __expf(lg[cc] - m);
        float lse = logf(ssum);
        for (int cc = 0; cc < NCLASSES; ++cc) out[g * NCLASSES + cc] = lg[cc] - m - lse;
    }
}

extern "C" void kernel_launch(void* const* d_in, const int* in_sizes, int n_in,
                              void* d_out, int out_size, void* d_ws, size_t ws_size,
                              hipStream_t stream) {
    float* out = (float*)d_out;

    // layout check: first mismatching index i -> out[:] = 5000+10*i
    static const int EXPECT[23] = {2560000, 2048000, 8192, 64, 512, 64, 4096, 64,
                                   49152, 768, 49152, 768, 49152, 768, 49152,
                                   12288, 192, 192, 192, 192, 3, 512000, 20000};
    int bad = -1;
    if (n_in != 23) bad = 99;
    else {
        for (int i = 0; i < 23; ++i) {
            if (in_sizes[i] != EXPECT[i]) { bad = i; break; }
        }
    }
    if (bad >= 0) {
        float val = (bad == 99) ? 4000.f : (5000.f + 10.f * bad);
        gt_write_const<<<1, 256, 0, stream>>>(out, out_size, val);
        return;
    }

    // ALL float inputs are float32 (reference is pure jnp.float32)
    const float* x        = (const float*)d_in[0];
    const float* edge_attr= (const float*)d_in[1];
    const float* node_W   = (const float*)d_in[2];
    const float* node_b   = (const float*)d_in[3];
    const float* e1_W     = (const float*)d_in[4];
    const float* e1_b     = (const float*)d_in[5];
    const float* e2_W     = (const float*)d_in[6];
    const float* e2_b     = (const float*)d_in[7];
    const float* Wq       = (const float*)d_in[8];
    const float* bq       = (const float*)d_in[9];
    const float* Wk       = (const float*)d_in[10];
    const float* bk       = (const float*)d_in[11];
    const float* Wv       = (const float*)d_in[12];
    const float* bv       = (const float*)d_in[13];
    const float* We       = (const float*)d_in[14];
    const float* Wskip    = (const float*)d_in[15];
    const float* bskip    = (const float*)d_in[16];
    const float* lng      = (const float*)d_in[17];
    const float* lnb      = (const float*)d_in[18];
    const float* cls_W    = (const float*)d_in[19];
    const float* cls_b    = (const float*)d_in[20];
    const int*   ei       = (const int*)d_in[21];
    const int*   batch    = (const int*)d_in[22];

    char* w = (char*)d_ws;
    auto alloc = [&](size_t bytes) -> char* {
        char* p = w;
        w += (bytes + 255) & ~(size_t)255;
        return p;
    };
    float* h     = (float*)alloc((size_t)NN * HID * 4);
    float* ef    = (float*)alloc((size_t)NE * HID * 4);
    float* q     = (float*)alloc((size_t)NN * HC * 4);
    float* k     = (float*)alloc((size_t)NN * HC * 4);
    float* v     = (float*)alloc((size_t)NN * HC * 4);
    float* alpha = (float*)alloc((size_t)NE * HEADS * 4);
    int*   cnt   = (int*)alloc((size_t)NN * 4);
    int*   rp    = (int*)alloc((size_t)(NN + 1) * 4);
    int*   cur   = (int*)alloc((size_t)NN * 4);
    int*   csr   = (int*)alloc((size_t)NE * 4);

    gt_node_proj<<<(NN + 3) / 4, 256, 0, stream>>>(x, node_W, node_b, h);
    gt_edge_mlp<<<(NE + 3) / 4, 256, 0, stream>>>(edge_attr, e1_W, e1_b, e2_W, e2_b, ef);
    gt_zero_i32<<<(NN + 255) / 256, 256, 0, stream>>>(cnt, NN);
    gt_count_dst<<<(NE + 255) / 256, 256, 0, stream>>>(ei, cnt);
    gt_scan_csr<<<1, 256, 0, stream>>>(cnt, rp, cur);
    gt_fill_csr<<<(NE + 255) / 256, 256, 0, stream>>>(ei, cur, csr);

    for (int l = 0; l < NLAYERS; ++l) {
        const float* Wq_l = Wq + (size_t)l * HID * HC;
        const float* bq_l = bq + (size_t)l * HC;
        const float* Wk_l = Wk + (size_t)l * HID * HC;
        const float* bk_l = bk + (size_t)l * HC;
        const float* Wv_l = Wv + (size_t)l * HID * HC;
        const float* bv_l = bv + (size_t)l * HC;
        const float* We_l = We + (size_t)l * HID * HC;
        const float* Ws_l = Wskip + (size_t)l * HID * HID;
        const float* bs_l = bskip + (size_t)l * HID;
        const float* lg_l = lng + (size_t)l * HID;
        const float* lb_l = lnb + (size_t)l * HID;

        gt_qkv<<<(NN + NPB - 1) / NPB, 256, 0, stream>>>(h, Wq_l, bq_l, Wk_l, bk_l, Wv_l, bv_l,
                                                         q, k, v);
        gt_alpha_direct<<<NE, 256, 0, stream>>>(q, k, ef, We_l, ei, alpha);
        gt_seg_softmax<<<(NN * HEADS + 255) / 256, 256, 0, stream>>>(rp, csr, alpha);
        gt_agg_direct<<<NN, 256, 0, stream>>>(v, ef, We_l, alpha, ei, rp, csr, Ws_l, bs_l,
                                              lg_l, lb_l, h);
    }

    gt_pool_classify<<<NGRAPHS, HID, 0, stream>>>(h, batch, cls_W, cls_b, out);
    gt_probe<<<1, 64, 0, stream>>>(h, lng, out);  // silent when healthy
}

// Round 11
// 2047.455 us; speedup vs baseline: 2.0290x; 2.0290x over previous
//
#include <hip/hip_runtime.h>
#include <hip/hip_bf16.h>
#include <math.h>

#define NN 20000
#define NE 256000
#define NODE_DIM_ 128
#define EDGE_DIM_ 8
#define HID 64
#define HEADS 4
#define NLAYERS 3
#define NCLASSES 3
#define NGRAPHS 64
#define HC 256  // HEADS*HID
#define NPB 8   // nodes per block in qkv

__device__ __forceinline__ int clampi(int x, int lo, int hi) { return min(max(x, lo), hi); }

// ---------------- diagnostics ----------------
__global__ void gt_write_const(float* out, int n, float val) {
    int i = blockIdx.x * blockDim.x + threadIdx.x;
    if (i < n) out[i] = val;
}

// Silent when healthy; encodes diagnostics into out when the pipeline is degenerate.
__global__ void gt_probe(const float* __restrict__ h, const float* __restrict__ lng,
                         float* out) {
    if (blockIdx.x != 0 || threadIdx.x != 0) return;
    float hbar = 0.f;
    for (int c = 0; c < HID; ++c) hbar += h[c];
    hbar *= (1.f / HID);
    float lng0 = lng[0];
    bool lngOK = fabsf(lng0 - 1.f) < 0.01f;
    bool hOK = (hbar >= 0.03f) && (hbar <= 3.f);
    if (lngOK && hOK) return;
    float v = 1000.f * fminf(fabsf(lng0), 3.f) + 100.f * fminf(fabsf(hbar), 5.f);
    for (int i = 0; i < NGRAPHS * NCLASSES; ++i) out[i] = 20.f + v;
}

// ---------------- utility ----------------
__global__ void gt_zero_i32(int* p, int n) {
    int i = blockIdx.x * blockDim.x + threadIdx.x;
    if (i < n) p[i] = 0;
}

// ---------------- h = x @ node_W + node_b  (4 nodes/block) ----------------
__global__ void gt_node_proj(const float* __restrict__ x, const float* __restrict__ W,
                             const float* __restrict__ b, float* __restrict__ h) {
    int t = threadIdx.x;            // 0..255
    int n = blockIdx.x * 4 + (t >> 6);
    int c = t & 63;
    __shared__ float xr[4][NODE_DIM_];
    for (int i = t; i < 4 * NODE_DIM_; i += 256) {
        int nn = blockIdx.x * 4 + i / NODE_DIM_;
        xr[i / NODE_DIM_][i % NODE_DIM_] = (nn < NN) ? x[(size_t)nn * NODE_DIM_ + i % NODE_DIM_] : 0.f;
    }
    __syncthreads();
    if (n >= NN) return;
    float acc = 0.f;
#pragma unroll 8
    for (int j = 0; j < NODE_DIM_; ++j) acc += xr[t >> 6][j] * W[j * HID + c];
    h[(size_t)n * HID + c] = acc + b[c];
}

// ---------------- e_feat = relu(ea@W1+b1)@W2+b2  (4 edges/block) ----------------
__global__ void gt_edge_mlp(const float* __restrict__ ea, const float* __restrict__ W1,
                            const float* __restrict__ b1, const float* __restrict__ W2,
                            const float* __restrict__ b2, float* __restrict__ ef) {
    int t = threadIdx.x;
    int sub = t >> 6, c = t & 63;
    int e = blockIdx.x * 4 + sub;
    __shared__ float a[4][EDGE_DIM_];
    __shared__ float t1[4][HID];
    for (int i = t; i < 4 * EDGE_DIM_; i += 256) {
        int eid = blockIdx.x * 4 + i / EDGE_DIM_;
        a[i / EDGE_DIM_][i % EDGE_DIM_] = (eid < NE) ? ea[(size_t)eid * EDGE_DIM_ + i % EDGE_DIM_] : 0.f;
    }
    __syncthreads();
    float acc = 0.f;
#pragma unroll
    for (int j = 0; j < EDGE_DIM_; ++j) acc += a[sub][j] * W1[j * HID + c];
    t1[sub][c] = fmaxf(acc + b1[c], 0.f);
    __syncthreads();
    if (e >= NE) return;
    float acc2 = 0.f;
#pragma unroll 8
    for (int j = 0; j < HID; ++j) acc2 += t1[sub][j] * W2[j * HID + c];
    ef[(size_t)e * HID + c] = acc2 + b2[c];
}

// ---------------- CSR build over dst ----------------
__global__ void gt_count_dst(const int* __restrict__ ei, int* cnt) {
    int e = blockIdx.x * blockDim.x + threadIdx.x;
    if (e < NE) {
        int d = clampi(ei[NE + e], 0, NN - 1);
        atomicAdd(&cnt[d], 1);
    }
}

__global__ void gt_scan_csr(const int* __restrict__ cnt, int* __restrict__ rp, int* __restrict__ cur) {
    __shared__ int part[256];
    int tid = threadIdx.x;
    const int CH = (NN + 255) / 256;  // 79
    int s0 = tid * CH, s1 = min(s0 + CH, NN);
    int s = 0;
    for (int i = s0; i < s1; ++i) s += cnt[i];
    part[tid] = s;
    __syncthreads();
    for (int off = 1; off < 256; off <<= 1) {
        int vv = (tid >= off) ? part[tid - off] : 0;
        __syncthreads();
        if (tid >= off) part[tid] += vv;
        __syncthreads();
    }
    int base = (tid == 0) ? 0 : part[tid - 1];
    for (int i = s0; i < s1; ++i) {
        rp[i] = base;
        cur[i] = base;
        base += cnt[i];
    }
    if (tid == 255) rp[NN] = part[255];
}

__global__ void gt_fill_csr(const int* __restrict__ ei, int* cur, int* csr) {
    int e = blockIdx.x * blockDim.x + threadIdx.x;
    if (e < NE) {
        int d = clampi(ei[NE + e], 0, NN - 1);
        int pos = atomicAdd(&cur[d], 1);
        if (pos >= 0 && pos < NE) csr[pos] = e;
    }
}

// ---------------- q,k,v,qe projections (8 nodes/block) ----------------
// qe[n, h*64+j] = sum_c q[n, h*64+c] * We[j*HC + h*64+c]   (q after bias)
__global__ void gt_qkv_qe(const float* __restrict__ h, const float* __restrict__ Wq,
                          const float* __restrict__ bq, const float* __restrict__ Wk,
                          const float* __restrict__ bk, const float* __restrict__ Wv,
                          const float* __restrict__ bv, const float* __restrict__ We,
                          float* __restrict__ q, float* __restrict__ k, float* __restrict__ v,
                          float* __restrict__ qe) {
    int t = threadIdx.x;  // 0..255
    int n0 = blockIdx.x * NPB;
    __shared__ float hs[NPB][HID];
    __shared__ float qs[NPB][HC];
    for (int i = t; i < NPB * HID; i += 256) {
        int nn = n0 + i / HID;
        hs[i / HID][i % HID] = (nn < NN) ? h[(size_t)nn * HID + i % HID] : 0.f;
    }
    __syncthreads();
    float aq[NPB], ak[NPB], av[NPB];
#pragma unroll
    for (int i = 0; i < NPB; ++i) { aq[i] = 0.f; ak[i] = 0.f; av[i] = 0.f; }
    for (int j = 0; j < HID; ++j) {
        float wq = Wq[j * HC + t];
        float wk = Wk[j * HC + t];
        float wv = Wv[j * HC + t];
#pragma unroll
        for (int i = 0; i < NPB; ++i) {
            aq[i] += hs[i][j] * wq;
            ak[i] += hs[i][j] * wk;
            av[i] += hs[i][j] * wv;
        }
    }
    float bqv = bq[t], bkv = bk[t], bvv = bv[t];
    for (int i = 0; i < NPB; ++i) {
        int nn = n0 + i;
        float qr = aq[i] + bqv;
        qs[i][t] = qr;
        if (nn < NN) {
            q[(size_t)nn * HC + t] = qr;
            k[(size_t)nn * HC + t] = ak[i] + bkv;
            v[(size_t)nn * HC + t] = av[i] + bvv;
        }
    }
    __syncthreads();
    int h2 = t >> 6, j = t & 63;
    const float* Wrow = We + (size_t)j * HC + h2 * 64;
    for (int i = 0; i < NPB; ++i) {
        int nn = n0 + i;
        if (nn < NN) {
            const float* qrow = &qs[i][h2 * 64];
            float acc = 0.f;
#pragma unroll 8
            for (int c = 0; c < 64; ++c) acc += qrow[c] * Wrow[c];
            qe[(size_t)nn * HC + t] = acc;
        }
    }
}

// ---------------- alpha[e,h] = scale*(q[dst]·k[src] + qe[dst]·ef[e]) ----------------
__global__ void gt_alpha_fact(const float* __restrict__ q, const float* __restrict__ k,
                              const float* __restrict__ qe, const float* __restrict__ ef,
                              const int* __restrict__ ei, float* __restrict__ alpha) {
    int e = blockIdx.x;
    int t = threadIdx.x;  // 256 = 4 waves = 4 heads
    int c = t & 63;
    int src = clampi(ei[e], 0, NN - 1);
    int dst = clampi(ei[NE + e], 0, NN - 1);
    float p = q[(size_t)dst * HC + t] * k[(size_t)src * HC + t] +
              qe[(size_t)dst * HC + t] * ef[(size_t)e * HID + c];
#pragma unroll
    for (int s = 32; s > 0; s >>= 1) p += __shfl_down(p, s, 64);
    if ((t & 63) == 0) alpha[e * HEADS + (t >> 6)] = p * 0.125f;  // 1/sqrt(64)
}

// ---------------- segment softmax over in-edges ----------------
__global__ void gt_seg_softmax(const int* __restrict__ rp, const int* __restrict__ csr,
                               float* __restrict__ alpha) {
    int idx = blockIdx.x * blockDim.x + threadIdx.x;
    if (idx >= NN * HEADS) return;
    int n = idx / HEADS, hh = idx % HEADS;
    int s0 = clampi(rp[n], 0, NE), s1 = clampi(rp[n + 1], s0, NE);
    if (s0 == s1) return;
    float m = -1e30f;
    for (int i = s0; i < s1; ++i) m = fmaxf(m, alpha[clampi(csr[i], 0, NE - 1) * HEADS + hh]);
    float den = 0.f;
    for (int i = s0; i < s1; ++i) den += __expf(alpha[clampi(csr[i], 0, NE - 1) * HEADS + hh] - m);
    float inv = 1.f / den;
    for (int i = s0; i < s1; ++i) {
        int e = clampi(csr[i], 0, NE - 1);
        alpha[e * HEADS + hh] = __expf(alpha[e * HEADS + hh] - m) * inv;
    }
}

// ---------------- aggregate (barrier-free loop) + project + mean heads + skip + LN + relu ----------------
__global__ void gt_agg_fact(const float* __restrict__ v, const float* __restrict__ ef,
                            const float* __restrict__ We, const float* __restrict__ alpha,
                            const int* __restrict__ ei, const int* __restrict__ rp,
                            const int* __restrict__ csr, const float* __restrict__ Wskip,
                            const float* __restrict__ bskip, const float* __restrict__ lng,
                            const float* __restrict__ lnb, float* __restrict__ h) {
    int n = blockIdx.x;
    int t = threadIdx.x;  // 0..255
    int h2 = t >> 6, c = t & 63;
    __shared__ float sS[HC];   // per-head alpha-weighted ef sums
    __shared__ float sC[HC];   // per-head conv output
    __shared__ float res[HID];
    if (t < HID) res[t] = h[(size_t)n * HID + t];
    int s0 = clampi(rp[n], 0, NE), s1 = clampi(rp[n + 1], s0, NE);
    float accv = 0.f, accs = 0.f;
    for (int i = s0; i < s1; ++i) {
        int e = clampi(csr[i], 0, NE - 1);
        float a = alpha[e * HEADS + h2];
        int src = clampi(ei[e], 0, NN - 1);
        accv += a * v[(size_t)src * HC + t];
        accs += a * ef[(size_t)e * HID + c];
    }
    sS[t] = accs;
    __syncthreads();
    // project per-head ef-sum through We: proj[t] = sum_j sS[h2*64+j] * We[j*HC + t]
    float proj = 0.f;
    const float* srow = &sS[h2 * 64];
#pragma unroll 8
    for (int j = 0; j < HID; ++j) proj += srow[j] * We[(size_t)j * HC + t];
    sC[t] = accv + proj;
    __syncthreads();
    if (t < HID) {
        float conv = 0.25f * (sC[t] + sC[HID + t] + sC[2 * HID + t] + sC[3 * HID + t]);
        float sk = bskip[t];
#pragma unroll 8
        for (int j = 0; j < HID; ++j) sk += res[j] * Wskip[j * HID + t];
        float y = conv + sk + res[t];
        float m = y;
#pragma unroll
        for (int s = 32; s > 0; s >>= 1) m += __shfl_xor(m, s, 64);
        m *= (1.f / HID);
        float d = y - m;
        float vv = d * d;
#pragma unroll
        for (int s = 32; s > 0; s >>= 1) vv += __shfl_xor(vv, s, 64);
        vv *= (1.f / HID);
        float o = d * rsqrtf(vv + 1e-5f) * lng[t] + lnb[t];
        h[(size_t)n * HID + t] = fmaxf(o, 0.f);
    }
}

// ---------------- pool (true count) + classifier ----------------
__global__ void gt_pool_classify(const float* __restrict__ h, const int* __restrict__ batch,
                                 const float* __restrict__ W, const float* __restrict__ b,
                                 float* __restrict__ out) {
    int g = blockIdx.x;   // 0..63
    int c = threadIdx.x;  // 0..63
    __shared__ float pooled[HID];
    __shared__ float lg[4];
    __shared__ int bounds[2];
    if (c < 2) {
        int target = g + c;
        int lo = 0, hi = NN;
        while (lo < hi) {
            int mid = (lo + hi) >> 1;
            if (batch[mid] < target) lo = mid + 1; else hi = mid;
        }
        bounds[c] = lo;
    }
    __syncthreads();
    int n0 = bounds[0], n1 = bounds[1];
    float s = 0.f;
    for (int n = n0; n < n1; ++n) s += h[(size_t)n * HID + c];
    float divf = fmaxf((float)(n1 - n0), 1.f);
    pooled[c] = s / divf;
    __syncthreads();
    if (c < NCLASSES) {
        float acc = 0.f;
        for (int j = 0; j < HID; ++j) acc += pooled[j] * W[j * NCLASSES + c];
        lg[c] = acc + b[c];
    }
    __syncthreads();
    if (c == 0) {
        float m = fmaxf(lg[0], fmaxf(lg[1], lg[2]));
        float ssum = 0.f;
        for (int cc = 0; cc < NCLASSES; ++cc) ssum += __expf(lg[cc] - m);
        float lse = logf(ssum);
        for (int cc = 0; cc < NCLASSES; ++cc) out[g * NCLASSES + cc] = lg[cc] - m - lse;
    }
}

extern "C" void kernel_launch(void* const* d_in, const int* in_sizes, int n_in,
                              void* d_out, int out_size, void* d_ws, size_t ws_size,
                              hipStream_t stream) {
    float* out = (float*)d_out;

    static const int EXPECT[23] = {2560000, 2048000, 8192, 64, 512, 64, 4096, 64,
                                   49152, 768, 49152, 768, 49152, 768, 49152,
                                   12288, 192, 192, 192, 192, 3, 512000, 20000};
    int bad = -1;
    if (n_in != 23) bad = 99;
    else {
        for (int i = 0; i < 23; ++i) {
            if (in_sizes[i] != EXPECT[i]) { bad = i; break; }
        }
    }
    if (bad >= 0) {
        float val = (bad == 99) ? 4000.f : (5000.f + 10.f * bad);
        gt_write_const<<<1, 256, 0, stream>>>(out, out_size, val);
        return;
    }

    const float* x        = (const float*)d_in[0];
    const float* edge_attr= (const float*)d_in[1];
    const float* node_W   = (const float*)d_in[2];
    const float* node_b   = (const float*)d_in[3];
    const float* e1_W     = (const float*)d_in[4];
    const float* e1_b     = (const float*)d_in[5];
    const float* e2_W     = (const float*)d_in[6];
    const float* e2_b     = (const float*)d_in[7];
    const float* Wq       = (const float*)d_in[8];
    const float* bq       = (const float*)d_in[9];
    const float* Wk       = (const float*)d_in[10];
    const float* bk       = (const float*)d_in[11];
    const float* Wv       = (const float*)d_in[12];
    const float* bv       = (const float*)d_in[13];
    const float* We       = (const float*)d_in[14];
    const float* Wskip    = (const float*)d_in[15];
    const float* bskip    = (const float*)d_in[16];
    const float* lng      = (const float*)d_in[17];
    const float* lnb      = (const float*)d_in[18];
    const float* cls_W    = (const float*)d_in[19];
    const float* cls_b    = (const float*)d_in[20];
    const int*   ei       = (const int*)d_in[21];
    const int*   batch    = (const int*)d_in[22];

    // ~158 MB workspace
    char* w = (char*)d_ws;
    auto alloc = [&](size_t bytes) -> char* {
        char* p = w;
        w += (bytes + 255) & ~(size_t)255;
        return p;
    };
    float* h     = (float*)alloc((size_t)NN * HID * 4);
    float* ef    = (float*)alloc((size_t)NE * HID * 4);
    float* q     = (float*)alloc((size_t)NN * HC * 4);
    float* k     = (float*)alloc((size_t)NN * HC * 4);
    float* v     = (float*)alloc((size_t)NN * HC * 4);
    float* qe    = (float*)alloc((size_t)NN * HC * 4);
    float* alpha = (float*)alloc((size_t)NE * HEADS * 4);
    int*   cnt   = (int*)alloc((size_t)NN * 4);
    int*   rp    = (int*)alloc((size_t)(NN + 1) * 4);
    int*   cur   = (int*)alloc((size_t)NN * 4);
    int*   csr   = (int*)alloc((size_t)NE * 4);

    gt_node_proj<<<(NN + 3) / 4, 256, 0, stream>>>(x, node_W, node_b, h);
    gt_edge_mlp<<<(NE + 3) / 4, 256, 0, stream>>>(edge_attr, e1_W, e1_b, e2_W, e2_b, ef);
    gt_zero_i32<<<(NN + 255) / 256, 256, 0, stream>>>(cnt, NN);
    gt_count_dst<<<(NE + 255) / 256, 256, 0, stream>>>(ei, cnt);
    gt_scan_csr<<<1, 256, 0, stream>>>(cnt, rp, cur);
    gt_fill_csr<<<(NE + 255) / 256, 256, 0, stream>>>(ei, cur, csr);

    for (int l = 0; l < NLAYERS; ++l) {
        const float* Wq_l = Wq + (size_t)l * HID * HC;
        const float* bq_l = bq + (size_t)l * HC;
        const float* Wk_l = Wk + (size_t)l * HID * HC;
        const float* bk_l = bk + (size_t)l * HC;
        const float* Wv_l = Wv + (size_t)l * HID * HC;
        const float* bv_l = bv + (size_t)l * HC;
        const float* We_l = We + (size_t)l * HID * HC;
        const float* Ws_l = Wskip + (size_t)l * HID * HID;
        const float* bs_l = bskip + (size_t)l * HID;
        const float* lg_l = lng + (size_t)l * HID;
        const float* lb_l = lnb + (size_t)l * HID;

        gt_qkv_qe<<<(NN + NPB - 1) / NPB, 256, 0, stream>>>(h, Wq_l, bq_l, Wk_l, bk_l, Wv_l, bv_l,
                                                            We_l, q, k, v, qe);
        gt_alpha_fact<<<NE, 256, 0, stream>>>(q, k, qe, ef, ei, alpha);
        gt_seg_softmax<<<(NN * HEADS + 255) / 256, 256, 0, stream>>>(rp, csr, alpha);
        gt_agg_fact<<<NN, 256, 0, stream>>>(v, ef, We_l, alpha, ei, rp, csr, Ws_l, bs_l,
                                            lg_l, lb_l, h);
    }

    gt_pool_classify<<<NGRAPHS, HID, 0, stream>>>(h, batch, cls_W, cls_b, out);
    gt_probe<<<1, 64, 0, stream>>>(h, lng, out);  // silent when healthy
}

// Round 12
// 1664.228 us; speedup vs baseline: 2.4963x; 1.2303x over previous
//
#include <hip/hip_runtime.h>
#include <hip/hip_bf16.h>
#include <math.h>

#define NN 20000
#define NE 256000
#define NODE_DIM_ 128
#define EDGE_DIM_ 8
#define HID 64
#define HEADS 4
#define NLAYERS 3
#define NCLASSES 3
#define NGRAPHS 64
#define HC 256  // HEADS*HID
#define NPB 8   // nodes per block in qkv

__device__ __forceinline__ int clampi(int x, int lo, int hi) { return min(max(x, lo), hi); }

// ---------------- diagnostics ----------------
__global__ void gt_write_const(float* out, int n, float val) {
    int i = blockIdx.x * blockDim.x + threadIdx.x;
    if (i < n) out[i] = val;
}

__global__ void gt_probe(const float* __restrict__ h, const float* __restrict__ lng,
                         float* out) {
    if (blockIdx.x != 0 || threadIdx.x != 0) return;
    float hbar = 0.f;
    for (int c = 0; c < HID; ++c) hbar += h[c];
    hbar *= (1.f / HID);
    float lng0 = lng[0];
    bool lngOK = fabsf(lng0 - 1.f) < 0.01f;
    bool hOK = (hbar >= 0.03f) && (hbar <= 3.f);
    if (lngOK && hOK) return;
    float v = 1000.f * fminf(fabsf(lng0), 3.f) + 100.f * fminf(fabsf(hbar), 5.f);
    for (int i = 0; i < NGRAPHS * NCLASSES; ++i) out[i] = 20.f + v;
}

// ---------------- utility ----------------
__global__ void gt_zero_i32(int* p, int n) {
    int i = blockIdx.x * blockDim.x + threadIdx.x;
    if (i < n) p[i] = 0;
}

// WeT[l][c*HC + h*64 + j] = We[l][j*HC + h*64 + c]  (3 layers, 48K elems)
__global__ void gt_transpose_we(const float* __restrict__ We, float* __restrict__ WeT) {
    int idx = blockIdx.x * blockDim.x + threadIdx.x;
    if (idx >= NLAYERS * HID * HC) return;
    int l = idx / (HID * HC);
    int r = idx % (HID * HC);
    int c = r / HC;
    int u = r % HC;           // u = h*64 + j
    int hh = u >> 6, j = u & 63;
    WeT[idx] = We[(size_t)l * HID * HC + (size_t)j * HC + hh * 64 + c];
}

// ---------------- h = x @ node_W + node_b  (4 nodes/block) ----------------
__global__ void gt_node_proj(const float* __restrict__ x, const float* __restrict__ W,
                             const float* __restrict__ b, float* __restrict__ h) {
    int t = threadIdx.x;            // 0..255
    int n = blockIdx.x * 4 + (t >> 6);
    int c = t & 63;
    __shared__ float xr[4][NODE_DIM_];
    for (int i = t; i < 4 * NODE_DIM_; i += 256) {
        int nn = blockIdx.x * 4 + i / NODE_DIM_;
        xr[i / NODE_DIM_][i % NODE_DIM_] = (nn < NN) ? x[(size_t)nn * NODE_DIM_ + i % NODE_DIM_] : 0.f;
    }
    __syncthreads();
    if (n >= NN) return;
    float acc = 0.f;
#pragma unroll 8
    for (int j = 0; j < NODE_DIM_; ++j) acc += xr[t >> 6][j] * W[j * HID + c];
    h[(size_t)n * HID + c] = acc + b[c];
}

// ---------------- e_feat = relu(ea@W1+b1)@W2+b2  (4 edges/block) ----------------
__global__ void gt_edge_mlp(const float* __restrict__ ea, const float* __restrict__ W1,
                            const float* __restrict__ b1, const float* __restrict__ W2,
                            const float* __restrict__ b2, float* __restrict__ ef) {
    int t = threadIdx.x;
    int sub = t >> 6, c = t & 63;
    int e = blockIdx.x * 4 + sub;
    __shared__ float a[4][EDGE_DIM_];
    __shared__ float t1[4][HID];
    for (int i = t; i < 4 * EDGE_DIM_; i += 256) {
        int eid = blockIdx.x * 4 + i / EDGE_DIM_;
        a[i / EDGE_DIM_][i % EDGE_DIM_] = (eid < NE) ? ea[(size_t)eid * EDGE_DIM_ + i % EDGE_DIM_] : 0.f;
    }
    __syncthreads();
    float acc = 0.f;
#pragma unroll
    for (int j = 0; j < EDGE_DIM_; ++j) acc += a[sub][j] * W1[j * HID + c];
    t1[sub][c] = fmaxf(acc + b1[c], 0.f);
    __syncthreads();
    if (e >= NE) return;
    float acc2 = 0.f;
#pragma unroll 8
    for (int j = 0; j < HID; ++j) acc2 += t1[sub][j] * W2[j * HID + c];
    ef[(size_t)e * HID + c] = acc2 + b2[c];
}

// ---------------- CSR build over dst ----------------
__global__ void gt_count_dst(const int* __restrict__ ei, int* cnt) {
    int e = blockIdx.x * blockDim.x + threadIdx.x;
    if (e < NE) {
        int d = clampi(ei[NE + e], 0, NN - 1);
        atomicAdd(&cnt[d], 1);
    }
}

__global__ void gt_scan_csr(const int* __restrict__ cnt, int* __restrict__ rp, int* __restrict__ cur) {
    __shared__ int part[256];
    int tid = threadIdx.x;
    const int CH = (NN + 255) / 256;  // 79
    int s0 = tid * CH, s1 = min(s0 + CH, NN);
    int s = 0;
    for (int i = s0; i < s1; ++i) s += cnt[i];
    part[tid] = s;
    __syncthreads();
    for (int off = 1; off < 256; off <<= 1) {
        int vv = (tid >= off) ? part[tid - off] : 0;
        __syncthreads();
        if (tid >= off) part[tid] += vv;
        __syncthreads();
    }
    int base = (tid == 0) ? 0 : part[tid - 1];
    for (int i = s0; i < s1; ++i) {
        rp[i] = base;
        cur[i] = base;
        base += cnt[i];
    }
    if (tid == 255) rp[NN] = part[255];
}

__global__ void gt_fill_csr(const int* __restrict__ ei, int* cur, int* csr) {
    int e = blockIdx.x * blockDim.x + threadIdx.x;
    if (e < NE) {
        int d = clampi(ei[NE + e], 0, NN - 1);
        int pos = atomicAdd(&cur[d], 1);
        if (pos >= 0 && pos < NE) csr[pos] = e;
    }
}

// ---------------- q,k,v,qe projections (8 nodes/block) ----------------
// qe computed via WeT so all global reads are coalesced.
__global__ void gt_qkv_qe(const float* __restrict__ h, const float* __restrict__ Wq,
                          const float* __restrict__ bq, const float* __restrict__ Wk,
                          const float* __restrict__ bk, const float* __restrict__ Wv,
                          const float* __restrict__ bv, const float* __restrict__ WeT,
                          float* __restrict__ q, float* __restrict__ k, float* __restrict__ v,
                          float* __restrict__ qe) {
    int t = threadIdx.x;  // 0..255
    int n0 = blockIdx.x * NPB;
    __shared__ float hs[NPB][HID];
    __shared__ float qs[NPB][HC];
    for (int i = t; i < NPB * HID; i += 256) {
        int nn = n0 + i / HID;
        hs[i / HID][i % HID] = (nn < NN) ? h[(size_t)nn * HID + i % HID] : 0.f;
    }
    __syncthreads();
    float aq[NPB], ak[NPB], av[NPB];
#pragma unroll
    for (int i = 0; i < NPB; ++i) { aq[i] = 0.f; ak[i] = 0.f; av[i] = 0.f; }
    for (int j = 0; j < HID; ++j) {
        float wq = Wq[j * HC + t];
        float wk = Wk[j * HC + t];
        float wv = Wv[j * HC + t];
#pragma unroll
        for (int i = 0; i < NPB; ++i) {
            aq[i] += hs[i][j] * wq;
            ak[i] += hs[i][j] * wk;
            av[i] += hs[i][j] * wv;
        }
    }
    float bqv = bq[t], bkv = bk[t], bvv = bv[t];
    for (int i = 0; i < NPB; ++i) {
        int nn = n0 + i;
        float qr = aq[i] + bqv;
        qs[i][t] = qr;
        if (nn < NN) {
            q[(size_t)nn * HC + t] = qr;
            k[(size_t)nn * HC + t] = ak[i] + bkv;
            v[(size_t)nn * HC + t] = av[i] + bvv;
        }
    }
    __syncthreads();
    // qe[n, t] = sum_c qs[n, h2*64+c] * WeT[c*HC + t]   (coalesced WeT reads)
    int h2 = t >> 6;
    float accq[NPB];
#pragma unroll
    for (int i = 0; i < NPB; ++i) accq[i] = 0.f;
    const float* qbase = &qs[0][h2 * 64];
    for (int c = 0; c < HID; ++c) {
        float wt = WeT[(size_t)c * HC + t];
#pragma unroll
        for (int i = 0; i < NPB; ++i) accq[i] += qs[i][h2 * 64 + c] * wt;
    }
    for (int i = 0; i < NPB; ++i) {
        int nn = n0 + i;
        if (nn < NN) qe[(size_t)nn * HC + t] = accq[i];
    }
    (void)qbase;
}

// ---------------- alpha[e,h] = scale*(q[dst]·k[src] + qe[dst]·ef[e]) ----------------
__global__ void gt_alpha_fact(const float* __restrict__ q, const float* __restrict__ k,
                              const float* __restrict__ qe, const float* __restrict__ ef,
                              const int* __restrict__ ei, float* __restrict__ alpha) {
    int e = blockIdx.x;
    int t = threadIdx.x;  // 256 = 4 waves = 4 heads
    int c = t & 63;
    int src = clampi(ei[e], 0, NN - 1);
    int dst = clampi(ei[NE + e], 0, NN - 1);
    float p = q[(size_t)dst * HC + t] * k[(size_t)src * HC + t] +
              qe[(size_t)dst * HC + t] * ef[(size_t)e * HID + c];
#pragma unroll
    for (int s = 32; s > 0; s >>= 1) p += __shfl_down(p, s, 64);
    if ((t & 63) == 0) alpha[e * HEADS + (t >> 6)] = p * 0.125f;  // 1/sqrt(64)
}

// ---------------- segment softmax over in-edges ----------------
__global__ void gt_seg_softmax(const int* __restrict__ rp, const int* __restrict__ csr,
                               float* __restrict__ alpha) {
    int idx = blockIdx.x * blockDim.x + threadIdx.x;
    if (idx >= NN * HEADS) return;
    int n = idx / HEADS, hh = idx % HEADS;
    int s0 = clampi(rp[n], 0, NE), s1 = clampi(rp[n + 1], s0, NE);
    if (s0 == s1) return;
    float m = -1e30f;
    for (int i = s0; i < s1; ++i) m = fmaxf(m, alpha[clampi(csr[i], 0, NE - 1) * HEADS + hh]);
    float den = 0.f;
    for (int i = s0; i < s1; ++i) den += __expf(alpha[clampi(csr[i], 0, NE - 1) * HEADS + hh] - m);
    float inv = 1.f / den;
    for (int i = s0; i < s1; ++i) {
        int e = clampi(csr[i], 0, NE - 1);
        alpha[e * HEADS + hh] = __expf(alpha[e * HEADS + hh] - m) * inv;
    }
}

// ---------------- aggregate (barrier-free loop) + project + mean heads + skip + LN + relu ----------------
__global__ void gt_agg_fact(const float* __restrict__ v, const float* __restrict__ ef,
                            const float* __restrict__ We, const float* __restrict__ alpha,
                            const int* __restrict__ ei, const int* __restrict__ rp,
                            const int* __restrict__ csr, const float* __restrict__ Wskip,
                            const float* __restrict__ bskip, const float* __restrict__ lng,
                            const float* __restrict__ lnb, float* __restrict__ h) {
    int n = blockIdx.x;
    int t = threadIdx.x;  // 0..255
    int h2 = t >> 6, c = t & 63;
    __shared__ float sS[HC];
    __shared__ float sC[HC];
    __shared__ float res[HID];
    if (t < HID) res[t] = h[(size_t)n * HID + t];
    int s0 = clampi(rp[n], 0, NE), s1 = clampi(rp[n + 1], s0, NE);
    float accv = 0.f, accs = 0.f;
    for (int i = s0; i < s1; ++i) {
        int e = clampi(csr[i], 0, NE - 1);
        float a = alpha[e * HEADS + h2];
        int src = clampi(ei[e], 0, NN - 1);
        accv += a * v[(size_t)src * HC + t];
        accs += a * ef[(size_t)e * HID + c];
    }
    sS[t] = accs;
    __syncthreads();
    float proj = 0.f;
    const float* srow = &sS[h2 * 64];
#pragma unroll 8
    for (int j = 0; j < HID; ++j) proj += srow[j] * We[(size_t)j * HC + t];
    sC[t] = accv + proj;
    __syncthreads();
    if (t < HID) {
        float conv = 0.25f * (sC[t] + sC[HID + t] + sC[2 * HID + t] + sC[3 * HID + t]);
        float sk = bskip[t];
#pragma unroll 8
        for (int j = 0; j < HID; ++j) sk += res[j] * Wskip[j * HID + t];
        float y = conv + sk + res[t];
        float m = y;
#pragma unroll
        for (int s = 32; s > 0; s >>= 1) m += __shfl_xor(m, s, 64);
        m *= (1.f / HID);
        float d = y - m;
        float vv = d * d;
#pragma unroll
        for (int s = 32; s > 0; s >>= 1) vv += __shfl_xor(vv, s, 64);
        vv *= (1.f / HID);
        float o = d * rsqrtf(vv + 1e-5f) * lng[t] + lnb[t];
        h[(size_t)n * HID + t] = fmaxf(o, 0.f);
    }
}

// ---------------- pool (true count) + classifier ----------------
__global__ void gt_pool_classify(const float* __restrict__ h, const int* __restrict__ batch,
                                 const float* __restrict__ W, const float* __restrict__ b,
                                 float* __restrict__ out) {
    int g = blockIdx.x;
    int c = threadIdx.x;
    __shared__ float pooled[HID];
    __shared__ float lg[4];
    __shared__ int bounds[2];
    if (c < 2) {
        int target = g + c;
        int lo = 0, hi = NN;
        while (lo < hi) {
            int mid = (lo + hi) >> 1;
            if (batch[mid] < target) lo = mid + 1; else hi = mid;
        }
        bounds[c] = lo;
    }
    __syncthreads();
    int n0 = bounds[0], n1 = bounds[1];
    float s = 0.f;
    for (int n = n0; n < n1; ++n) s += h[(size_t)n * HID + c];
    float divf = fmaxf((float)(n1 - n0), 1.f);
    pooled[c] = s / divf;
    __syncthreads();
    if (c < NCLASSES) {
        float acc = 0.f;
        for (int j = 0; j < HID; ++j) acc += pooled[j] * W[j * NCLASSES + c];
        lg[c] = acc + b[c];
    }
    __syncthreads();
    if (c == 0) {
        float m = fmaxf(lg[0], fmaxf(lg[1], lg[2]));
        float ssum = 0.f;
        for (int cc = 0; cc < NCLASSES; ++cc) ssum += __expf(lg[cc] - m);
        float lse = logf(ssum);
        for (int cc = 0; cc < NCLASSES; ++cc) out[g * NCLASSES + cc] = lg[cc] - m - lse;
    }
}

extern "C" void kernel_launch(void* const* d_in, const int* in_sizes, int n_in,
                              void* d_out, int out_size, void* d_ws, size_t ws_size,
                              hipStream_t stream) {
    float* out = (float*)d_out;

    static const int EXPECT[23] = {2560000, 2048000, 8192, 64, 512, 64, 4096, 64,
                                   49152, 768, 49152, 768, 49152, 768, 49152,
                                   12288, 192, 192, 192, 192, 3, 512000, 20000};
    int bad = -1;
    if (n_in != 23) bad = 99;
    else {
        for (int i = 0; i < 23; ++i) {
            if (in_sizes[i] != EXPECT[i]) { bad = i; break; }
        }
    }
    if (bad >= 0) {
        float val = (bad == 99) ? 4000.f : (5000.f + 10.f * bad);
        gt_write_const<<<1, 256, 0, stream>>>(out, out_size, val);
        return;
    }

    const float* x        = (const float*)d_in[0];
    const float* edge_attr= (const float*)d_in[1];
    const float* node_W   = (const float*)d_in[2];
    const float* node_b   = (const float*)d_in[3];
    const float* e1_W     = (const float*)d_in[4];
    const float* e1_b     = (const float*)d_in[5];
    const float* e2_W     = (const float*)d_in[6];
    const float* e2_b     = (const float*)d_in[7];
    const float* Wq       = (const float*)d_in[8];
    const float* bq       = (const float*)d_in[9];
    const float* Wk       = (const float*)d_in[10];
    const float* bk       = (const float*)d_in[11];
    const float* Wv       = (const float*)d_in[12];
    const float* bv       = (const float*)d_in[13];
    const float* We       = (const float*)d_in[14];
    const float* Wskip    = (const float*)d_in[15];
    const float* bskip    = (const float*)d_in[16];
    const float* lng      = (const float*)d_in[17];
    const float* lnb      = (const float*)d_in[18];
    const float* cls_W    = (const float*)d_in[19];
    const float* cls_b    = (const float*)d_in[20];
    const int*   ei       = (const int*)d_in[21];
    const int*   batch    = (const int*)d_in[22];

    char* w = (char*)d_ws;
    auto alloc = [&](size_t bytes) -> char* {
        char* p = w;
        w += (bytes + 255) & ~(size_t)255;
        return p;
    };
    float* h     = (float*)alloc((size_t)NN * HID * 4);
    float* ef    = (float*)alloc((size_t)NE * HID * 4);
    float* q     = (float*)alloc((size_t)NN * HC * 4);
    float* k     = (float*)alloc((size_t)NN * HC * 4);
    float* v     = (float*)alloc((size_t)NN * HC * 4);
    float* qe    = (float*)alloc((size_t)NN * HC * 4);
    float* alpha = (float*)alloc((size_t)NE * HEADS * 4);
    float* WeT   = (float*)alloc((size_t)NLAYERS * HID * HC * 4);
    int*   cnt   = (int*)alloc((size_t)NN * 4);
    int*   rp    = (int*)alloc((size_t)(NN + 1) * 4);
    int*   cur   = (int*)alloc((size_t)NN * 4);
    int*   csr   = (int*)alloc((size_t)NE * 4);

    gt_node_proj<<<(NN + 3) / 4, 256, 0, stream>>>(x, node_W, node_b, h);
    gt_edge_mlp<<<(NE + 3) / 4, 256, 0, stream>>>(edge_attr, e1_W, e1_b, e2_W, e2_b, ef);
    gt_transpose_we<<<(NLAYERS * HID * HC + 255) / 256, 256, 0, stream>>>(We, WeT);
    gt_zero_i32<<<(NN + 255) / 256, 256, 0, stream>>>(cnt, NN);
    gt_count_dst<<<(NE + 255) / 256, 256, 0, stream>>>(ei, cnt);
    gt_scan_csr<<<1, 256, 0, stream>>>(cnt, rp, cur);
    gt_fill_csr<<<(NE + 255) / 256, 256, 0, stream>>>(ei, cur, csr);

    for (int l = 0; l < NLAYERS; ++l) {
        const float* Wq_l = Wq + (size_t)l * HID * HC;
        const float* bq_l = bq + (size_t)l * HC;
        const float* Wk_l = Wk + (size_t)l * HID * HC;
        const float* bk_l = bk + (size_t)l * HC;
        const float* Wv_l = Wv + (size_t)l * HID * HC;
        const float* bv_l = bv + (size_t)l * HC;
        const float* We_l = We + (size_t)l * HID * HC;
        const float* WeT_l= WeT + (size_t)l * HID * HC;
        const float* Ws_l = Wskip + (size_t)l * HID * HID;
        const float* bs_l = bskip + (size_t)l * HID;
        const float* lg_l = lng + (size_t)l * HID;
        const float* lb_l = lnb + (size_t)l * HID;

        gt_qkv_qe<<<(NN + NPB - 1) / NPB, 256, 0, stream>>>(h, Wq_l, bq_l, Wk_l, bk_l, Wv_l, bv_l,
                                                            WeT_l, q, k, v, qe);
        gt_alpha_fact<<<NE, 256, 0, stream>>>(q, k, qe, ef, ei, alpha);
        gt_seg_softmax<<<(NN * HEADS + 255) / 256, 256, 0, stream>>>(rp, csr, alpha);
        gt_agg_fact<<<NN, 256, 0, stream>>>(v, ef, We_l, alpha, ei, rp, csr, Ws_l, bs_l,
                                            lg_l, lb_l, h);
    }

    gt_pool_classify<<<NGRAPHS, HID, 0, stream>>>(h, batch, cls_W, cls_b, out);
    gt_probe<<<1, 64, 0, stream>>>(h, lng, out);  // silent when healthy
}

// Round 13
// 1396.026 us; speedup vs baseline: 2.9758x; 1.1921x over previous
//
#include <hip/hip_runtime.h>
#include <hip/hip_bf16.h>
#include <math.h>

#define NN 20000
#define NE 256000
#define NODE_DIM_ 128
#define EDGE_DIM_ 8
#define HID 64
#define HEADS 4
#define NLAYERS 3
#define NCLASSES 3
#define NGRAPHS 64
#define HC 256  // HEADS*HID
#define NPB 8   // nodes per block in qkv
#define ECHUNK 256  // edges staged in LDS per chunk in agg

__device__ __forceinline__ int clampi(int x, int lo, int hi) { return min(max(x, lo), hi); }

// ---------------- diagnostics ----------------
__global__ void gt_write_const(float* out, int n, float val) {
    int i = blockIdx.x * blockDim.x + threadIdx.x;
    if (i < n) out[i] = val;
}

__global__ void gt_probe(const float* __restrict__ h, const float* __restrict__ lng,
                         float* out) {
    if (blockIdx.x != 0 || threadIdx.x != 0) return;
    float hbar = 0.f;
    for (int c = 0; c < HID; ++c) hbar += h[c];
    hbar *= (1.f / HID);
    float lng0 = lng[0];
    bool lngOK = fabsf(lng0 - 1.f) < 0.01f;
    bool hOK = (hbar >= 0.03f) && (hbar <= 3.f);
    if (lngOK && hOK) return;
    float v = 1000.f * fminf(fabsf(lng0), 3.f) + 100.f * fminf(fabsf(hbar), 5.f);
    for (int i = 0; i < NGRAPHS * NCLASSES; ++i) out[i] = 20.f + v;
}

// ---------------- utility ----------------
__global__ void gt_zero_i32(int* p, int n) {
    int i = blockIdx.x * blockDim.x + threadIdx.x;
    if (i < n) p[i] = 0;
}

// WeT[l][c*HC + h*64 + j] = We[l][j*HC + h*64 + c]
__global__ void gt_transpose_we(const float* __restrict__ We, float* __restrict__ WeT) {
    int idx = blockIdx.x * blockDim.x + threadIdx.x;
    if (idx >= NLAYERS * HID * HC) return;
    int l = idx / (HID * HC);
    int r = idx % (HID * HC);
    int c = r / HC;
    int u = r % HC;
    int hh = u >> 6, j = u & 63;
    WeT[idx] = We[(size_t)l * HID * HC + (size_t)j * HC + hh * 64 + c];
}

// ---------------- h = x @ node_W + node_b  (4 nodes/block) ----------------
__global__ void gt_node_proj(const float* __restrict__ x, const float* __restrict__ W,
                             const float* __restrict__ b, float* __restrict__ h) {
    int t = threadIdx.x;
    int n = blockIdx.x * 4 + (t >> 6);
    int c = t & 63;
    __shared__ float xr[4][NODE_DIM_];
    for (int i = t; i < 4 * NODE_DIM_; i += 256) {
        int nn = blockIdx.x * 4 + i / NODE_DIM_;
        xr[i / NODE_DIM_][i % NODE_DIM_] = (nn < NN) ? x[(size_t)nn * NODE_DIM_ + i % NODE_DIM_] : 0.f;
    }
    __syncthreads();
    if (n >= NN) return;
    float acc = 0.f;
#pragma unroll 8
    for (int j = 0; j < NODE_DIM_; ++j) acc += xr[t >> 6][j] * W[j * HID + c];
    h[(size_t)n * HID + c] = acc + b[c];
}

// ---------------- e_feat = relu(ea@W1+b1)@W2+b2  (4 edges/block) ----------------
__global__ void gt_edge_mlp(const float* __restrict__ ea, const float* __restrict__ W1,
                            const float* __restrict__ b1, const float* __restrict__ W2,
                            const float* __restrict__ b2, float* __restrict__ ef) {
    int t = threadIdx.x;
    int sub = t >> 6, c = t & 63;
    int e = blockIdx.x * 4 + sub;
    __shared__ float a[4][EDGE_DIM_];
    __shared__ float t1[4][HID];
    for (int i = t; i < 4 * EDGE_DIM_; i += 256) {
        int eid = blockIdx.x * 4 + i / EDGE_DIM_;
        a[i / EDGE_DIM_][i % EDGE_DIM_] = (eid < NE) ? ea[(size_t)eid * EDGE_DIM_ + i % EDGE_DIM_] : 0.f;
    }
    __syncthreads();
    float acc = 0.f;
#pragma unroll
    for (int j = 0; j < EDGE_DIM_; ++j) acc += a[sub][j] * W1[j * HID + c];
    t1[sub][c] = fmaxf(acc + b1[c], 0.f);
    __syncthreads();
    if (e >= NE) return;
    float acc2 = 0.f;
#pragma unroll 8
    for (int j = 0; j < HID; ++j) acc2 += t1[sub][j] * W2[j * HID + c];
    ef[(size_t)e * HID + c] = acc2 + b2[c];
}

// ---------------- CSR build over dst ----------------
__global__ void gt_count_dst(const int* __restrict__ ei, int* cnt) {
    int e = blockIdx.x * blockDim.x + threadIdx.x;
    if (e < NE) {
        int d = clampi(ei[NE + e], 0, NN - 1);
        atomicAdd(&cnt[d], 1);
    }
}

__global__ void gt_scan_csr(const int* __restrict__ cnt, int* __restrict__ rp, int* __restrict__ cur) {
    __shared__ int part[256];
    int tid = threadIdx.x;
    const int CH = (NN + 255) / 256;
    int s0 = tid * CH, s1 = min(s0 + CH, NN);
    int s = 0;
    for (int i = s0; i < s1; ++i) s += cnt[i];
    part[tid] = s;
    __syncthreads();
    for (int off = 1; off < 256; off <<= 1) {
        int vv = (tid >= off) ? part[tid - off] : 0;
        __syncthreads();
        if (tid >= off) part[tid] += vv;
        __syncthreads();
    }
    int base = (tid == 0) ? 0 : part[tid - 1];
    for (int i = s0; i < s1; ++i) {
        rp[i] = base;
        cur[i] = base;
        base += cnt[i];
    }
    if (tid == 255) rp[NN] = part[255];
}

__global__ void gt_fill_csr(const int* __restrict__ ei, int* cur, int* csr) {
    int e = blockIdx.x * blockDim.x + threadIdx.x;
    if (e < NE) {
        int d = clampi(ei[NE + e], 0, NN - 1);
        int pos = atomicAdd(&cur[d], 1);
        if (pos >= 0 && pos < NE) csr[pos] = e;
    }
}

// ---------------- q,k,v,qe projections (8 nodes/block) ----------------
__global__ void gt_qkv_qe(const float* __restrict__ h, const float* __restrict__ Wq,
                          const float* __restrict__ bq, const float* __restrict__ Wk,
                          const float* __restrict__ bk, const float* __restrict__ Wv,
                          const float* __restrict__ bv, const float* __restrict__ WeT,
                          float* __restrict__ q, float* __restrict__ k, float* __restrict__ v,
                          float* __restrict__ qe) {
    int t = threadIdx.x;
    int n0 = blockIdx.x * NPB;
    __shared__ float hs[NPB][HID];
    __shared__ float qs[NPB][HC];
    for (int i = t; i < NPB * HID; i += 256) {
        int nn = n0 + i / HID;
        hs[i / HID][i % HID] = (nn < NN) ? h[(size_t)nn * HID + i % HID] : 0.f;
    }
    __syncthreads();
    float aq[NPB], ak[NPB], av[NPB];
#pragma unroll
    for (int i = 0; i < NPB; ++i) { aq[i] = 0.f; ak[i] = 0.f; av[i] = 0.f; }
    for (int j = 0; j < HID; ++j) {
        float wq = Wq[j * HC + t];
        float wk = Wk[j * HC + t];
        float wv = Wv[j * HC + t];
#pragma unroll
        for (int i = 0; i < NPB; ++i) {
            aq[i] += hs[i][j] * wq;
            ak[i] += hs[i][j] * wk;
            av[i] += hs[i][j] * wv;
        }
    }
    float bqv = bq[t], bkv = bk[t], bvv = bv[t];
    for (int i = 0; i < NPB; ++i) {
        int nn = n0 + i;
        float qr = aq[i] + bqv;
        qs[i][t] = qr;
        if (nn < NN) {
            q[(size_t)nn * HC + t] = qr;
            k[(size_t)nn * HC + t] = ak[i] + bkv;
            v[(size_t)nn * HC + t] = av[i] + bvv;
        }
    }
    __syncthreads();
    int h2 = t >> 6;
    float accq[NPB];
#pragma unroll
    for (int i = 0; i < NPB; ++i) accq[i] = 0.f;
    for (int c = 0; c < HID; ++c) {
        float wt = WeT[(size_t)c * HC + t];
#pragma unroll
        for (int i = 0; i < NPB; ++i) accq[i] += qs[i][h2 * 64 + c] * wt;
    }
    for (int i = 0; i < NPB; ++i) {
        int nn = n0 + i;
        if (nn < NN) qe[(size_t)nn * HC + t] = accq[i];
    }
}

// ---------------- alpha[e,h] = scale*(q[dst]·k[src] + qe[dst]·ef[e]) ----------------
__global__ void gt_alpha_fact(const float* __restrict__ q, const float* __restrict__ k,
                              const float* __restrict__ qe, const float* __restrict__ ef,
                              const int* __restrict__ ei, float* __restrict__ alpha) {
    int e = blockIdx.x;
    int t = threadIdx.x;
    int c = t & 63;
    int src = clampi(ei[e], 0, NN - 1);
    int dst = clampi(ei[NE + e], 0, NN - 1);
    float p = q[(size_t)dst * HC + t] * k[(size_t)src * HC + t] +
              qe[(size_t)dst * HC + t] * ef[(size_t)e * HID + c];
#pragma unroll
    for (int s = 32; s > 0; s >>= 1) p += __shfl_down(p, s, 64);
    if ((t & 63) == 0) alpha[e * HEADS + (t >> 6)] = p * 0.125f;
}

// ---------------- segment softmax over in-edges ----------------
__global__ void gt_seg_softmax(const int* __restrict__ rp, const int* __restrict__ csr,
                               float* __restrict__ alpha) {
    int idx = blockIdx.x * blockDim.x + threadIdx.x;
    if (idx >= NN * HEADS) return;
    int n = idx / HEADS, hh = idx % HEADS;
    int s0 = clampi(rp[n], 0, NE), s1 = clampi(rp[n + 1], s0, NE);
    if (s0 == s1) return;
    float m = -1e30f;
    for (int i = s0; i < s1; ++i) m = fmaxf(m, alpha[clampi(csr[i], 0, NE - 1) * HEADS + hh]);
    float den = 0.f;
    for (int i = s0; i < s1; ++i) den += __expf(alpha[clampi(csr[i], 0, NE - 1) * HEADS + hh] - m);
    float inv = 1.f / den;
    for (int i = s0; i < s1; ++i) {
        int e = clampi(csr[i], 0, NE - 1);
        alpha[e * HEADS + hh] = __expf(alpha[e * HEADS + hh] - m) * inv;
    }
}

// ---------------- aggregate: LDS-staged edge metadata (breaks dependent chain) ----------------
__global__ void gt_agg_fact(const float* __restrict__ v, const float* __restrict__ ef,
                            const float* __restrict__ We, const float* __restrict__ alpha,
                            const int* __restrict__ ei, const int* __restrict__ rp,
                            const int* __restrict__ csr, const float* __restrict__ Wskip,
                            const float* __restrict__ bskip, const float* __restrict__ lng,
                            const float* __restrict__ lnb, float* __restrict__ h) {
    int n = blockIdx.x;
    int t = threadIdx.x;  // 0..255
    int h2 = t >> 6, c = t & 63;
    __shared__ int sE[ECHUNK];
    __shared__ int sSrc[ECHUNK];
    __shared__ float4 sA[ECHUNK];
    __shared__ float sS[HC];
    __shared__ float sC[HC];
    __shared__ float res[HID];
    if (t < HID) res[t] = h[(size_t)n * HID + t];
    int s0 = clampi(rp[n], 0, NE), s1 = clampi(rp[n + 1], s0, NE);
    float accv = 0.f, accs = 0.f;
    for (int base = s0; base < s1; base += ECHUNK) {
        int m = min(ECHUNK, s1 - base);
        __syncthreads();
        // parallel metadata stage: one edge per thread, no dependent chain
        if (t < m) {
            int e = clampi(csr[base + t], 0, NE - 1);
            sE[t] = e;
            sSrc[t] = clampi(ei[e], 0, NN - 1);
            sA[t] = *(const float4*)&alpha[e * HEADS];
        }
        __syncthreads();
        // gather loop: all addresses known; loads pipeline deeply
#pragma unroll 4
        for (int i = 0; i < m; ++i) {
            float a = ((const float*)&sA[i])[h2];
            accv += a * v[(size_t)sSrc[i] * HC + t];
            accs += a * ef[(size_t)sE[i] * HID + c];
        }
    }
    sS[t] = accs;
    __syncthreads();
    float proj = 0.f;
    const float* srow = &sS[h2 * 64];
#pragma unroll 8
    for (int j = 0; j < HID; ++j) proj += srow[j] * We[(size_t)j * HC + t];
    sC[t] = accv + proj;
    __syncthreads();
    if (t < HID) {
        float conv = 0.25f * (sC[t] + sC[HID + t] + sC[2 * HID + t] + sC[3 * HID + t]);
        float sk = bskip[t];
#pragma unroll 8
        for (int j = 0; j < HID; ++j) sk += res[j] * Wskip[j * HID + t];
        float y = conv + sk + res[t];
        float m = y;
#pragma unroll
        for (int s = 32; s > 0; s >>= 1) m += __shfl_xor(m, s, 64);
        m *= (1.f / HID);
        float d = y - m;
        float vv = d * d;
#pragma unroll
        for (int s = 32; s > 0; s >>= 1) vv += __shfl_xor(vv, s, 64);
        vv *= (1.f / HID);
        float o = d * rsqrtf(vv + 1e-5f) * lng[t] + lnb[t];
        h[(size_t)n * HID + t] = fmaxf(o, 0.f);
    }
}

// ---------------- pool (true count) + classifier ----------------
__global__ void gt_pool_classify(const float* __restrict__ h, const int* __restrict__ batch,
                                 const float* __restrict__ W, const float* __restrict__ b,
                                 float* __restrict__ out) {
    int g = blockIdx.x;
    int c = threadIdx.x;
    __shared__ float pooled[HID];
    __shared__ float lg[4];
    __shared__ int bounds[2];
    if (c < 2) {
        int target = g + c;
        int lo = 0, hi = NN;
        while (lo < hi) {
            int mid = (lo + hi) >> 1;
            if (batch[mid] < target) lo = mid + 1; else hi = mid;
        }
        bounds[c] = lo;
    }
    __syncthreads();
    int n0 = bounds[0], n1 = bounds[1];
    float s = 0.f;
    for (int n = n0; n < n1; ++n) s += h[(size_t)n * HID + c];
    float divf = fmaxf((float)(n1 - n0), 1.f);
    pooled[c] = s / divf;
    __syncthreads();
    if (c < NCLASSES) {
        float acc = 0.f;
        for (int j = 0; j < HID; ++j) acc += pooled[j] * W[j * NCLASSES + c];
        lg[c] = acc + b[c];
    }
    __syncthreads();
    if (c == 0) {
        float m = fmaxf(lg[0], fmaxf(lg[1], lg[2]));
        float ssum = 0.f;
        for (int cc = 0; cc < NCLASSES; ++cc) ssum += __expf(lg[cc] - m);
        float lse = logf(ssum);
        for (int cc = 0; cc < NCLASSES; ++cc) out[g * NCLASSES + cc] = lg[cc] - m - lse;
    }
}

extern "C" void kernel_launch(void* const* d_in, const int* in_sizes, int n_in,
                              void* d_out, int out_size, void* d_ws, size_t ws_size,
                              hipStream_t stream) {
    float* out = (float*)d_out;

    static const int EXPECT[23] = {2560000, 2048000, 8192, 64, 512, 64, 4096, 64,
                                   49152, 768, 49152, 768, 49152, 768, 49152,
                                   12288, 192, 192, 192, 192, 3, 512000, 20000};
    int bad = -1;
    if (n_in != 23) bad = 99;
    else {
        for (int i = 0; i < 23; ++i) {
            if (in_sizes[i] != EXPECT[i]) { bad = i; break; }
        }
    }
    if (bad >= 0) {
        float val = (bad == 99) ? 4000.f : (5000.f + 10.f * bad);
        gt_write_const<<<1, 256, 0, stream>>>(out, out_size, val);
        return;
    }

    const float* x        = (const float*)d_in[0];
    const float* edge_attr= (const float*)d_in[1];
    const float* node_W   = (const float*)d_in[2];
    const float* node_b   = (const float*)d_in[3];
    const float* e1_W     = (const float*)d_in[4];
    const float* e1_b     = (const float*)d_in[5];
    const float* e2_W     = (const float*)d_in[6];
    const float* e2_b     = (const float*)d_in[7];
    const float* Wq       = (const float*)d_in[8];
    const float* bq       = (const float*)d_in[9];
    const float* Wk       = (const float*)d_in[10];
    const float* bk       = (const float*)d_in[11];
    const float* Wv       = (const float*)d_in[12];
    const float* bv       = (const float*)d_in[13];
    const float* We       = (const float*)d_in[14];
    const float* Wskip    = (const float*)d_in[15];
    const float* bskip    = (const float*)d_in[16];
    const float* lng      = (const float*)d_in[17];
    const float* lnb      = (const float*)d_in[18];
    const float* cls_W    = (const float*)d_in[19];
    const float* cls_b    = (const float*)d_in[20];
    const int*   ei       = (const int*)d_in[21];
    const int*   batch    = (const int*)d_in[22];

    char* w = (char*)d_ws;
    auto alloc = [&](size_t bytes) -> char* {
        char* p = w;
        w += (bytes + 255) & ~(size_t)255;
        return p;
    };
    float* h     = (float*)alloc((size_t)NN * HID * 4);
    float* ef    = (float*)alloc((size_t)NE * HID * 4);
    float* q     = (float*)alloc((size_t)NN * HC * 4);
    float* k     = (float*)alloc((size_t)NN * HC * 4);
    float* v     = (float*)alloc((size_t)NN * HC * 4);
    float* qe    = (float*)alloc((size_t)NN * HC * 4);
    float* alpha = (float*)alloc((size_t)NE * HEADS * 4);
    float* WeT   = (float*)alloc((size_t)NLAYERS * HID * HC * 4);
    int*   cnt   = (int*)alloc((size_t)NN * 4);
    int*   rp    = (int*)alloc((size_t)(NN + 1) * 4);
    int*   cur   = (int*)alloc((size_t)NN * 4);
    int*   csr   = (int*)alloc((size_t)NE * 4);

    gt_node_proj<<<(NN + 3) / 4, 256, 0, stream>>>(x, node_W, node_b, h);
    gt_edge_mlp<<<(NE + 3) / 4, 256, 0, stream>>>(edge_attr, e1_W, e1_b, e2_W, e2_b, ef);
    gt_transpose_we<<<(NLAYERS * HID * HC + 255) / 256, 256, 0, stream>>>(We, WeT);
    gt_zero_i32<<<(NN + 255) / 256, 256, 0, stream>>>(cnt, NN);
    gt_count_dst<<<(NE + 255) / 256, 256, 0, stream>>>(ei, cnt);
    gt_scan_csr<<<1, 256, 0, stream>>>(cnt, rp, cur);
    gt_fill_csr<<<(NE + 255) / 256, 256, 0, stream>>>(ei, cur, csr);

    for (int l = 0; l < NLAYERS; ++l) {
        const float* Wq_l = Wq + (size_t)l * HID * HC;
        const float* bq_l = bq + (size_t)l * HC;
        const float* Wk_l = Wk + (size_t)l * HID * HC;
        const float* bk_l = bk + (size_t)l * HC;
        const float* Wv_l = Wv + (size_t)l * HID * HC;
        const float* bv_l = bv + (size_t)l * HC;
        const float* We_l = We + (size_t)l * HID * HC;
        const float* WeT_l= WeT + (size_t)l * HID * HC;
        const float* Ws_l = Wskip + (size_t)l * HID * HID;
        const float* bs_l = bskip + (size_t)l * HID;
        const float* lg_l = lng + (size_t)l * HID;
        const float* lb_l = lnb + (size_t)l * HID;

        gt_qkv_qe<<<(NN + NPB - 1) / NPB, 256, 0, stream>>>(h, Wq_l, bq_l, Wk_l, bk_l, Wv_l, bv_l,
                                                            WeT_l, q, k, v, qe);
        gt_alpha_fact<<<NE, 256, 0, stream>>>(q, k, qe, ef, ei, alpha);
        gt_seg_softmax<<<(NN * HEADS + 255) / 256, 256, 0, stream>>>(rp, csr, alpha);
        gt_agg_fact<<<NN, 256, 0, stream>>>(v, ef, We_l, alpha, ei, rp, csr, Ws_l, bs_l,
                                            lg_l, lb_l, h);
    }

    gt_pool_classify<<<NGRAPHS, HID, 0, stream>>>(h, batch, cls_W, cls_b, out);
    gt_probe<<<1, 64, 0, stream>>>(h, lng, out);  // silent when healthy
}

// Round 14
// 1080.204 us; speedup vs baseline: 3.8459x; 1.2924x over previous
//
#include <hip/hip_runtime.h>
#include <hip/hip_bf16.h>
#include <math.h>

#define NN 20000
#define NE 256000
#define NODE_DIM_ 128
#define EDGE_DIM_ 8
#define HID 64
#define HEADS 4
#define NLAYERS 3
#define NCLASSES 3
#define NGRAPHS 64
#define HC 256  // HEADS*HID
#define NPB 8   // nodes per block in qkv
#define ECHUNK 256  // edges staged in LDS per chunk
#define EB 64       // edges per block in edge_mlp

__device__ __forceinline__ int clampi(int x, int lo, int hi) { return min(max(x, lo), hi); }

// ---------------- diagnostics ----------------
__global__ void gt_write_const(float* out, int n, float val) {
    int i = blockIdx.x * blockDim.x + threadIdx.x;
    if (i < n) out[i] = val;
}

__global__ void gt_probe(const float* __restrict__ h, const float* __restrict__ lng,
                         float* out) {
    if (blockIdx.x != 0 || threadIdx.x != 0) return;
    float hbar = 0.f;
    for (int c = 0; c < HID; ++c) hbar += h[c];
    hbar *= (1.f / HID);
    float lng0 = lng[0];
    bool lngOK = fabsf(lng0 - 1.f) < 0.01f;
    bool hOK = (hbar >= 0.03f) && (hbar <= 3.f);
    if (lngOK && hOK) return;
    float v = 1000.f * fminf(fabsf(lng0), 3.f) + 100.f * fminf(fabsf(hbar), 5.f);
    for (int i = 0; i < NGRAPHS * NCLASSES; ++i) out[i] = 20.f + v;
}

// ---------------- utility ----------------
__global__ void gt_zero_i32(int* p, int n) {
    int i = blockIdx.x * blockDim.x + threadIdx.x;
    if (i < n) p[i] = 0;
}

// WeT[l][c*HC + h*64 + j] = We[l][j*HC + h*64 + c]
__global__ void gt_transpose_we(const float* __restrict__ We, float* __restrict__ WeT) {
    int idx = blockIdx.x * blockDim.x + threadIdx.x;
    if (idx >= NLAYERS * HID * HC) return;
    int l = idx / (HID * HC);
    int r = idx % (HID * HC);
    int c = r / HC;
    int u = r % HC;
    int hh = u >> 6, j = u & 63;
    WeT[idx] = We[(size_t)l * HID * HC + (size_t)j * HC + hh * 64 + c];
}

// ---------------- h = x @ node_W + node_b  (4 nodes/block) ----------------
__global__ void gt_node_proj(const float* __restrict__ x, const float* __restrict__ W,
                             const float* __restrict__ b, float* __restrict__ h) {
    int t = threadIdx.x;
    int n = blockIdx.x * 4 + (t >> 6);
    int c = t & 63;
    __shared__ float xr[4][NODE_DIM_];
    for (int i = t; i < 4 * NODE_DIM_; i += 256) {
        int nn = blockIdx.x * 4 + i / NODE_DIM_;
        xr[i / NODE_DIM_][i % NODE_DIM_] = (nn < NN) ? x[(size_t)nn * NODE_DIM_ + i % NODE_DIM_] : 0.f;
    }
    __syncthreads();
    if (n >= NN) return;
    float acc = 0.f;
#pragma unroll 8
    for (int j = 0; j < NODE_DIM_; ++j) acc += xr[t >> 6][j] * W[j * HID + c];
    h[(size_t)n * HID + c] = acc + b[c];
}

// ---------------- edge MLP: 64-edge GEMM tile per block ----------------
__global__ void gt_edge_mlp(const float* __restrict__ ea, const float* __restrict__ W1,
                            const float* __restrict__ b1, const float* __restrict__ W2,
                            const float* __restrict__ b2, float* __restrict__ ef) {
    int t = threadIdx.x;        // 0..255
    int c = t & 63, slot = t >> 6;  // 4 slots x 16 edges
    int e0 = blockIdx.x * EB;
    __shared__ float aS[EB][EDGE_DIM_];    // 2 KB
    __shared__ float t1s[EB][HID];         // 16 KB
    // stage 64 edges' attrs (512 floats, coalesced)
    for (int i = t; i < EB * EDGE_DIM_; i += 256) {
        ((float*)aS)[i] = ea[(size_t)e0 * EDGE_DIM_ + i];
    }
    float w1r[EDGE_DIM_];
#pragma unroll
    for (int j = 0; j < EDGE_DIM_; ++j) w1r[j] = W1[j * HID + c];
    float b1c = b1[c], b2c = b2[c];
    __syncthreads();
    // phase 1: t1 = relu(a @ W1 + b1), 16 edges per thread
#pragma unroll
    for (int es16 = 0; es16 < 16; ++es16) {
        int es = slot * 16 + es16;
        float acc = b1c;
#pragma unroll
        for (int j = 0; j < EDGE_DIM_; ++j) acc += aS[es][j] * w1r[j];
        t1s[es][c] = fmaxf(acc, 0.f);
    }
    __syncthreads();
    // phase 2: ef = t1 @ W2 + b2, j-outer with 16 independent accumulators
    float acc2[16];
#pragma unroll
    for (int i = 0; i < 16; ++i) acc2[i] = b2c;
    for (int j = 0; j < HID; ++j) {
        float w = W2[j * HID + c];
#pragma unroll
        for (int es16 = 0; es16 < 16; ++es16) acc2[es16] += t1s[slot * 16 + es16][j] * w;
    }
#pragma unroll
    for (int es16 = 0; es16 < 16; ++es16) {
        int es = slot * 16 + es16;
        ef[(size_t)(e0 + es) * HID + c] = acc2[es16];
    }
}

// ---------------- CSR build over dst ----------------
__global__ void gt_count_dst(const int* __restrict__ ei, int* cnt) {
    int e = blockIdx.x * blockDim.x + threadIdx.x;
    if (e < NE) {
        int d = clampi(ei[NE + e], 0, NN - 1);
        atomicAdd(&cnt[d], 1);
    }
}

__global__ void gt_scan_csr(const int* __restrict__ cnt, int* __restrict__ rp, int* __restrict__ cur) {
    __shared__ int part[256];
    int tid = threadIdx.x;
    const int CH = (NN + 255) / 256;
    int s0 = tid * CH, s1 = min(s0 + CH, NN);
    int s = 0;
    for (int i = s0; i < s1; ++i) s += cnt[i];
    part[tid] = s;
    __syncthreads();
    for (int off = 1; off < 256; off <<= 1) {
        int vv = (tid >= off) ? part[tid - off] : 0;
        __syncthreads();
        if (tid >= off) part[tid] += vv;
        __syncthreads();
    }
    int base = (tid == 0) ? 0 : part[tid - 1];
    for (int i = s0; i < s1; ++i) {
        rp[i] = base;
        cur[i] = base;
        base += cnt[i];
    }
    if (tid == 255) rp[NN] = part[255];
}

__global__ void gt_fill_csr(const int* __restrict__ ei, int* cur, int* csr) {
    int e = blockIdx.x * blockDim.x + threadIdx.x;
    if (e < NE) {
        int d = clampi(ei[NE + e], 0, NN - 1);
        int pos = atomicAdd(&cur[d], 1);
        if (pos >= 0 && pos < NE) csr[pos] = e;
    }
}

// ---------------- q,k,v,qe projections (8 nodes/block) ----------------
__global__ void gt_qkv_qe(const float* __restrict__ h, const float* __restrict__ Wq,
                          const float* __restrict__ bq, const float* __restrict__ Wk,
                          const float* __restrict__ bk, const float* __restrict__ Wv,
                          const float* __restrict__ bv, const float* __restrict__ WeT,
                          float* __restrict__ q, float* __restrict__ k, float* __restrict__ v,
                          float* __restrict__ qe) {
    int t = threadIdx.x;
    int n0 = blockIdx.x * NPB;
    __shared__ float hs[NPB][HID];
    __shared__ float qs[NPB][HC];
    for (int i = t; i < NPB * HID; i += 256) {
        int nn = n0 + i / HID;
        hs[i / HID][i % HID] = (nn < NN) ? h[(size_t)nn * HID + i % HID] : 0.f;
    }
    __syncthreads();
    float aq[NPB], ak[NPB], av[NPB];
#pragma unroll
    for (int i = 0; i < NPB; ++i) { aq[i] = 0.f; ak[i] = 0.f; av[i] = 0.f; }
    for (int j = 0; j < HID; ++j) {
        float wq = Wq[j * HC + t];
        float wk = Wk[j * HC + t];
        float wv = Wv[j * HC + t];
#pragma unroll
        for (int i = 0; i < NPB; ++i) {
            aq[i] += hs[i][j] * wq;
            ak[i] += hs[i][j] * wk;
            av[i] += hs[i][j] * wv;
        }
    }
    float bqv = bq[t], bkv = bk[t], bvv = bv[t];
    for (int i = 0; i < NPB; ++i) {
        int nn = n0 + i;
        float qr = aq[i] + bqv;
        qs[i][t] = qr;
        if (nn < NN) {
            q[(size_t)nn * HC + t] = qr;
            k[(size_t)nn * HC + t] = ak[i] + bkv;
            v[(size_t)nn * HC + t] = av[i] + bvv;
        }
    }
    __syncthreads();
    int h2 = t >> 6;
    float accq[NPB];
#pragma unroll
    for (int i = 0; i < NPB; ++i) accq[i] = 0.f;
    for (int c = 0; c < HID; ++c) {
        float wt = WeT[(size_t)c * HC + t];
#pragma unroll
        for (int i = 0; i < NPB; ++i) accq[i] += qs[i][h2 * 64 + c] * wt;
    }
    for (int i = 0; i < NPB; ++i) {
        int nn = n0 + i;
        if (nn < NN) qe[(size_t)nn * HC + t] = accq[i];
    }
}

// ---------------- alpha, dst-major: block per node, wave per edge ----------------
__global__ void gt_alpha_node(const float* __restrict__ q, const float* __restrict__ qe,
                              const float* __restrict__ k, const float* __restrict__ ef,
                              const int* __restrict__ rp, const int* __restrict__ csr,
                              const int* __restrict__ ei, float* __restrict__ alpha) {
    int n = blockIdx.x;
    int t = threadIdx.x;  // 256 = 4 waves
    int lane = t & 63, wave = t >> 6;
    __shared__ float sQ[HC];
    __shared__ float sQe[HC];
    __shared__ int sE[ECHUNK];
    __shared__ int sSrc[ECHUNK];
    sQ[t] = q[(size_t)n * HC + t];
    sQe[t] = qe[(size_t)n * HC + t];
    int s0 = clampi(rp[n], 0, NE), s1 = clampi(rp[n + 1], s0, NE);
    for (int base = s0; base < s1; base += ECHUNK) {
        int m = min(ECHUNK, s1 - base);
        __syncthreads();
        if (t < m) {
            int e = clampi(csr[base + t], 0, NE - 1);
            sE[t] = e;
            sSrc[t] = clampi(ei[e], 0, NN - 1);
        }
        __syncthreads();
        for (int i = wave; i < m; i += 4) {
            int e = sE[i];
            const float* kk = &k[(size_t)sSrc[i] * HC];
            float efc = ef[(size_t)e * HID + lane];
            float p0 = sQ[lane] * kk[lane] + sQe[lane] * efc;
            float p1 = sQ[64 + lane] * kk[64 + lane] + sQe[64 + lane] * efc;
            float p2 = sQ[128 + lane] * kk[128 + lane] + sQe[128 + lane] * efc;
            float p3 = sQ[192 + lane] * kk[192 + lane] + sQe[192 + lane] * efc;
#pragma unroll
            for (int s = 32; s > 0; s >>= 1) {
                p0 += __shfl_down(p0, s, 64);
                p1 += __shfl_down(p1, s, 64);
                p2 += __shfl_down(p2, s, 64);
                p3 += __shfl_down(p3, s, 64);
            }
            if (lane == 0) {
                float4 r;
                r.x = p0 * 0.125f; r.y = p1 * 0.125f; r.z = p2 * 0.125f; r.w = p3 * 0.125f;
                *(float4*)&alpha[e * HEADS] = r;
            }
        }
    }
}

// ---------------- segment softmax over in-edges ----------------
__global__ void gt_seg_softmax(const int* __restrict__ rp, const int* __restrict__ csr,
                               float* __restrict__ alpha) {
    int idx = blockIdx.x * blockDim.x + threadIdx.x;
    if (idx >= NN * HEADS) return;
    int n = idx / HEADS, hh = idx % HEADS;
    int s0 = clampi(rp[n], 0, NE), s1 = clampi(rp[n + 1], s0, NE);
    if (s0 == s1) return;
    float m = -1e30f;
    for (int i = s0; i < s1; ++i) m = fmaxf(m, alpha[clampi(csr[i], 0, NE - 1) * HEADS + hh]);
    float den = 0.f;
    for (int i = s0; i < s1; ++i) den += __expf(alpha[clampi(csr[i], 0, NE - 1) * HEADS + hh] - m);
    float inv = 1.f / den;
    for (int i = s0; i < s1; ++i) {
        int e = clampi(csr[i], 0, NE - 1);
        alpha[e * HEADS + hh] = __expf(alpha[e * HEADS + hh] - m) * inv;
    }
}

// ---------------- aggregate: LDS-staged edge metadata ----------------
__global__ void gt_agg_fact(const float* __restrict__ v, const float* __restrict__ ef,
                            const float* __restrict__ We, const float* __restrict__ alpha,
                            const int* __restrict__ ei, const int* __restrict__ rp,
                            const int* __restrict__ csr, const float* __restrict__ Wskip,
                            const float* __restrict__ bskip, const float* __restrict__ lng,
                            const float* __restrict__ lnb, float* __restrict__ h) {
    int n = blockIdx.x;
    int t = threadIdx.x;
    int h2 = t >> 6, c = t & 63;
    __shared__ int sE[ECHUNK];
    __shared__ int sSrc[ECHUNK];
    __shared__ float4 sA[ECHUNK];
    __shared__ float sS[HC];
    __shared__ float sC[HC];
    __shared__ float res[HID];
    if (t < HID) res[t] = h[(size_t)n * HID + t];
    int s0 = clampi(rp[n], 0, NE), s1 = clampi(rp[n + 1], s0, NE);
    float accv = 0.f, accs = 0.f;
    for (int base = s0; base < s1; base += ECHUNK) {
        int m = min(ECHUNK, s1 - base);
        __syncthreads();
        if (t < m) {
            int e = clampi(csr[base + t], 0, NE - 1);
            sE[t] = e;
            sSrc[t] = clampi(ei[e], 0, NN - 1);
            sA[t] = *(const float4*)&alpha[e * HEADS];
        }
        __syncthreads();
#pragma unroll 4
        for (int i = 0; i < m; ++i) {
            float a = ((const float*)&sA[i])[h2];
            accv += a * v[(size_t)sSrc[i] * HC + t];
            accs += a * ef[(size_t)sE[i] * HID + c];
        }
    }
    sS[t] = accs;
    __syncthreads();
    float proj = 0.f;
    const float* srow = &sS[h2 * 64];
#pragma unroll 8
    for (int j = 0; j < HID; ++j) proj += srow[j] * We[(size_t)j * HC + t];
    sC[t] = accv + proj;
    __syncthreads();
    if (t < HID) {
        float conv = 0.25f * (sC[t] + sC[HID + t] + sC[2 * HID + t] + sC[3 * HID + t]);
        float sk = bskip[t];
#pragma unroll 8
        for (int j = 0; j < HID; ++j) sk += res[j] * Wskip[j * HID + t];
        float y = conv + sk + res[t];
        float m = y;
#pragma unroll
        for (int s = 32; s > 0; s >>= 1) m += __shfl_xor(m, s, 64);
        m *= (1.f / HID);
        float d = y - m;
        float vv = d * d;
#pragma unroll
        for (int s = 32; s > 0; s >>= 1) vv += __shfl_xor(vv, s, 64);
        vv *= (1.f / HID);
        float o = d * rsqrtf(vv + 1e-5f) * lng[t] + lnb[t];
        h[(size_t)n * HID + t] = fmaxf(o, 0.f);
    }
}

// ---------------- pool (true count) + classifier ----------------
__global__ void gt_pool_classify(const float* __restrict__ h, const int* __restrict__ batch,
                                 const float* __restrict__ W, const float* __restrict__ b,
                                 float* __restrict__ out) {
    int g = blockIdx.x;
    int c = threadIdx.x;
    __shared__ float pooled[HID];
    __shared__ float lg[4];
    __shared__ int bounds[2];
    if (c < 2) {
        int target = g + c;
        int lo = 0, hi = NN;
        while (lo < hi) {
            int mid = (lo + hi) >> 1;
            if (batch[mid] < target) lo = mid + 1; else hi = mid;
        }
        bounds[c] = lo;
    }
    __syncthreads();
    int n0 = bounds[0], n1 = bounds[1];
    float s = 0.f;
    for (int n = n0; n < n1; ++n) s += h[(size_t)n * HID + c];
    float divf = fmaxf((float)(n1 - n0), 1.f);
    pooled[c] = s / divf;
    __syncthreads();
    if (c < NCLASSES) {
        float acc = 0.f;
        for (int j = 0; j < HID; ++j) acc += pooled[j] * W[j * NCLASSES + c];
        lg[c] = acc + b[c];
    }
    __syncthreads();
    if (c == 0) {
        float m = fmaxf(lg[0], fmaxf(lg[1], lg[2]));
        float ssum = 0.f;
        for (int cc = 0; cc < NCLASSES; ++cc) ssum += __expf(lg[cc] - m);
        float lse = logf(ssum);
        for (int cc = 0; cc < NCLASSES; ++cc) out[g * NCLASSES + cc] = lg[cc] - m - lse;
    }
}

extern "C" void kernel_launch(void* const* d_in, const int* in_sizes, int n_in,
                              void* d_out, int out_size, void* d_ws, size_t ws_size,
                              hipStream_t stream) {
    float* out = (float*)d_out;

    static const int EXPECT[23] = {2560000, 2048000, 8192, 64, 512, 64, 4096, 64,
                                   49152, 768, 49152, 768, 49152, 768, 49152,
                                   12288, 192, 192, 192, 192, 3, 512000, 20000};
    int bad = -1;
    if (n_in != 23) bad = 99;
    else {
        for (int i = 0; i < 23; ++i) {
            if (in_sizes[i] != EXPECT[i]) { bad = i; break; }
        }
    }
    if (bad >= 0) {
        float val = (bad == 99) ? 4000.f : (5000.f + 10.f * bad);
        gt_write_const<<<1, 256, 0, stream>>>(out, out_size, val);
        return;
    }

    const float* x        = (const float*)d_in[0];
    const float* edge_attr= (const float*)d_in[1];
    const float* node_W   = (const float*)d_in[2];
    const float* node_b   = (const float*)d_in[3];
    const float* e1_W     = (const float*)d_in[4];
    const float* e1_b     = (const float*)d_in[5];
    const float* e2_W     = (const float*)d_in[6];
    const float* e2_b     = (const float*)d_in[7];
    const float* Wq       = (const float*)d_in[8];
    const float* bq       = (const float*)d_in[9];
    const float* Wk       = (const float*)d_in[10];
    const float* bk       = (const float*)d_in[11];
    const float* Wv       = (const float*)d_in[12];
    const float* bv       = (const float*)d_in[13];
    const float* We       = (const float*)d_in[14];
    const float* Wskip    = (const float*)d_in[15];
    const float* bskip    = (const float*)d_in[16];
    const float* lng      = (const float*)d_in[17];
    const float* lnb      = (const float*)d_in[18];
    const float* cls_W    = (const float*)d_in[19];
    const float* cls_b    = (const float*)d_in[20];
    const int*   ei       = (const int*)d_in[21];
    const int*   batch    = (const int*)d_in[22];

    char* w = (char*)d_ws;
    auto alloc = [&](size_t bytes) -> char* {
        char* p = w;
        w += (bytes + 255) & ~(size_t)255;
        return p;
    };
    float* h     = (float*)alloc((size_t)NN * HID * 4);
    float* ef    = (float*)alloc((size_t)NE * HID * 4);
    float* q     = (float*)alloc((size_t)NN * HC * 4);
    float* k     = (float*)alloc((size_t)NN * HC * 4);
    float* v     = (float*)alloc((size_t)NN * HC * 4);
    float* qe    = (float*)alloc((size_t)NN * HC * 4);
    float* alpha = (float*)alloc((size_t)NE * HEADS * 4);
    float* WeT   = (float*)alloc((size_t)NLAYERS * HID * HC * 4);
    int*   cnt   = (int*)alloc((size_t)NN * 4);
    int*   rp    = (int*)alloc((size_t)(NN + 1) * 4);
    int*   cur   = (int*)alloc((size_t)NN * 4);
    int*   csr   = (int*)alloc((size_t)NE * 4);

    gt_node_proj<<<(NN + 3) / 4, 256, 0, stream>>>(x, node_W, node_b, h);
    gt_edge_mlp<<<NE / EB, 256, 0, stream>>>(edge_attr, e1_W, e1_b, e2_W, e2_b, ef);
    gt_transpose_we<<<(NLAYERS * HID * HC + 255) / 256, 256, 0, stream>>>(We, WeT);
    gt_zero_i32<<<(NN + 255) / 256, 256, 0, stream>>>(cnt, NN);
    gt_count_dst<<<(NE + 255) / 256, 256, 0, stream>>>(ei, cnt);
    gt_scan_csr<<<1, 256, 0, stream>>>(cnt, rp, cur);
    gt_fill_csr<<<(NE + 255) / 256, 256, 0, stream>>>(ei, cur, csr);

    for (int l = 0; l < NLAYERS; ++l) {
        const float* Wq_l = Wq + (size_t)l * HID * HC;
        const float* bq_l = bq + (size_t)l * HC;
        const float* Wk_l = Wk + (size_t)l * HID * HC;
        const float* bk_l = bk + (size_t)l * HC;
        const float* Wv_l = Wv + (size_t)l * HID * HC;
        const float* bv_l = bv + (size_t)l * HC;
        const float* We_l = We + (size_t)l * HID * HC;
        const float* WeT_l= WeT + (size_t)l * HID * HC;
        const float* Ws_l = Wskip + (size_t)l * HID * HID;
        const float* bs_l = bskip + (size_t)l * HID;
        const float* lg_l = lng + (size_t)l * HID;
        const float* lb_l = lnb + (size_t)l * HID;

        gt_qkv_qe<<<(NN + NPB - 1) / NPB, 256, 0, stream>>>(h, Wq_l, bq_l, Wk_l, bk_l, Wv_l, bv_l,
                                                            WeT_l, q, k, v, qe);
        gt_alpha_node<<<NN, 256, 0, stream>>>(q, qe, k, ef, rp, csr, ei, alpha);
        gt_seg_softmax<<<(NN * HEADS + 255) / 256, 256, 0, stream>>>(rp, csr, alpha);
        gt_agg_fact<<<NN, 256, 0, stream>>>(v, ef, We_l, alpha, ei, rp, csr, Ws_l, bs_l,
                                            lg_l, lb_l, h);
    }

    gt_pool_classify<<<NGRAPHS, HID, 0, stream>>>(h, batch, cls_W, cls_b, out);
    gt_probe<<<1, 64, 0, stream>>>(h, lng, out);  // silent when healthy
}

// Round 15
// 879.880 us; speedup vs baseline: 4.7215x; 1.2277x over previous
//
#include <hip/hip_runtime.h>
#include <hip/hip_bf16.h>
#include <math.h>

#define NN 20000
#define NE 256000
#define NODE_DIM_ 128
#define EDGE_DIM_ 8
#define HID 64
#define HEADS 4
#define NLAYERS 3
#define NCLASSES 3
#define NGRAPHS 64
#define HC 256  // HEADS*HID
#define NPB 8   // nodes per block in qkv
#define ECHUNK 256  // edges staged per chunk in fused attn
#define EB 64       // edges per block in edge_mlp

typedef __hip_bfloat16 bf16;

__device__ __forceinline__ float B2F(bf16 x) { return __bfloat162float(x); }
__device__ __forceinline__ bf16 F2B(float x) { return __float2bfloat16(x); }
__device__ __forceinline__ int clampi(int x, int lo, int hi) { return min(max(x, lo), hi); }

// ---------------- diagnostics ----------------
__global__ void gt_write_const(float* out, int n, float val) {
    int i = blockIdx.x * blockDim.x + threadIdx.x;
    if (i < n) out[i] = val;
}

// ---------------- utility ----------------
__global__ void gt_zero_i32(int* p, int n) {
    int i = blockIdx.x * blockDim.x + threadIdx.x;
    if (i < n) p[i] = 0;
}

// WeT[l][c*HC + h*64 + j] = We[l][j*HC + h*64 + c]
__global__ void gt_transpose_we(const float* __restrict__ We, float* __restrict__ WeT) {
    int idx = blockIdx.x * blockDim.x + threadIdx.x;
    if (idx >= NLAYERS * HID * HC) return;
    int l = idx / (HID * HC);
    int r = idx % (HID * HC);
    int c = r / HC;
    int u = r % HC;
    int hh = u >> 6, j = u & 63;
    WeT[idx] = We[(size_t)l * HID * HC + (size_t)j * HC + hh * 64 + c];
}

// ---------------- h = x @ node_W + node_b  (4 nodes/block) ----------------
__global__ void gt_node_proj(const float* __restrict__ x, const float* __restrict__ W,
                             const float* __restrict__ b, float* __restrict__ h) {
    int t = threadIdx.x;
    int n = blockIdx.x * 4 + (t >> 6);
    int c = t & 63;
    __shared__ float xr[4][NODE_DIM_];
    for (int i = t; i < 4 * NODE_DIM_; i += 256) {
        int nn = blockIdx.x * 4 + i / NODE_DIM_;
        xr[i / NODE_DIM_][i % NODE_DIM_] = (nn < NN) ? x[(size_t)nn * NODE_DIM_ + i % NODE_DIM_] : 0.f;
    }
    __syncthreads();
    if (n >= NN) return;
    float acc = 0.f;
#pragma unroll 8
    for (int j = 0; j < NODE_DIM_; ++j) acc += xr[t >> 6][j] * W[j * HID + c];
    h[(size_t)n * HID + c] = acc + b[c];
}

// ---------------- edge MLP: 64-edge GEMM tile per block, bf16 out ----------------
__global__ void gt_edge_mlp(const float* __restrict__ ea, const float* __restrict__ W1,
                            const float* __restrict__ b1, const float* __restrict__ W2,
                            const float* __restrict__ b2, bf16* __restrict__ ef) {
    int t = threadIdx.x;
    int c = t & 63, slot = t >> 6;
    int e0 = blockIdx.x * EB;
    __shared__ float aS[EB][EDGE_DIM_];
    __shared__ float t1s[EB][HID];
    for (int i = t; i < EB * EDGE_DIM_; i += 256) {
        ((float*)aS)[i] = ea[(size_t)e0 * EDGE_DIM_ + i];
    }
    float w1r[EDGE_DIM_];
#pragma unroll
    for (int j = 0; j < EDGE_DIM_; ++j) w1r[j] = W1[j * HID + c];
    float b1c = b1[c], b2c = b2[c];
    __syncthreads();
#pragma unroll
    for (int es16 = 0; es16 < 16; ++es16) {
        int es = slot * 16 + es16;
        float acc = b1c;
#pragma unroll
        for (int j = 0; j < EDGE_DIM_; ++j) acc += aS[es][j] * w1r[j];
        t1s[es][c] = fmaxf(acc, 0.f);
    }
    __syncthreads();
    float acc2[16];
#pragma unroll
    for (int i = 0; i < 16; ++i) acc2[i] = b2c;
    for (int j = 0; j < HID; ++j) {
        float w = W2[j * HID + c];
#pragma unroll
        for (int es16 = 0; es16 < 16; ++es16) acc2[es16] += t1s[slot * 16 + es16][j] * w;
    }
#pragma unroll
    for (int es16 = 0; es16 < 16; ++es16) {
        int es = slot * 16 + es16;
        ef[(size_t)(e0 + es) * HID + c] = F2B(acc2[es16]);
    }
}

// ---------------- CSR build over dst ----------------
__global__ void gt_count_dst(const int* __restrict__ ei, int* cnt) {
    int e = blockIdx.x * blockDim.x + threadIdx.x;
    if (e < NE) {
        int d = clampi(ei[NE + e], 0, NN - 1);
        atomicAdd(&cnt[d], 1);
    }
}

__global__ void gt_scan_csr(const int* __restrict__ cnt, int* __restrict__ rp, int* __restrict__ cur) {
    __shared__ int part[256];
    int tid = threadIdx.x;
    const int CH = (NN + 255) / 256;
    int s0 = tid * CH, s1 = min(s0 + CH, NN);
    int s = 0;
    for (int i = s0; i < s1; ++i) s += cnt[i];
    part[tid] = s;
    __syncthreads();
    for (int off = 1; off < 256; off <<= 1) {
        int vv = (tid >= off) ? part[tid - off] : 0;
        __syncthreads();
        if (tid >= off) part[tid] += vv;
        __syncthreads();
    }
    int base = (tid == 0) ? 0 : part[tid - 1];
    for (int i = s0; i < s1; ++i) {
        rp[i] = base;
        cur[i] = base;
        base += cnt[i];
    }
    if (tid == 255) rp[NN] = part[255];
}

__global__ void gt_fill_csr(const int* __restrict__ ei, int* cur, int* csr) {
    int e = blockIdx.x * blockDim.x + threadIdx.x;
    if (e < NE) {
        int d = clampi(ei[NE + e], 0, NN - 1);
        int pos = atomicAdd(&cur[d], 1);
        if (pos >= 0 && pos < NE) csr[pos] = e;
    }
}

// ---------------- q,k,v,qe projections (8 nodes/block); k,v bf16 out ----------------
__global__ void gt_qkv_qe(const float* __restrict__ h, const float* __restrict__ Wq,
                          const float* __restrict__ bq, const float* __restrict__ Wk,
                          const float* __restrict__ bk, const float* __restrict__ Wv,
                          const float* __restrict__ bv, const float* __restrict__ WeT,
                          float* __restrict__ q, bf16* __restrict__ k, bf16* __restrict__ v,
                          float* __restrict__ qe) {
    int t = threadIdx.x;
    int n0 = blockIdx.x * NPB;
    __shared__ float hs[NPB][HID];
    __shared__ float qs[NPB][HC];
    for (int i = t; i < NPB * HID; i += 256) {
        int nn = n0 + i / HID;
        hs[i / HID][i % HID] = (nn < NN) ? h[(size_t)nn * HID + i % HID] : 0.f;
    }
    __syncthreads();
    float aq[NPB], ak[NPB], av[NPB];
#pragma unroll
    for (int i = 0; i < NPB; ++i) { aq[i] = 0.f; ak[i] = 0.f; av[i] = 0.f; }
    for (int j = 0; j < HID; ++j) {
        float wq = Wq[j * HC + t];
        float wk = Wk[j * HC + t];
        float wv = Wv[j * HC + t];
#pragma unroll
        for (int i = 0; i < NPB; ++i) {
            aq[i] += hs[i][j] * wq;
            ak[i] += hs[i][j] * wk;
            av[i] += hs[i][j] * wv;
        }
    }
    float bqv = bq[t], bkv = bk[t], bvv = bv[t];
    for (int i = 0; i < NPB; ++i) {
        int nn = n0 + i;
        float qr = aq[i] + bqv;
        qs[i][t] = qr;
        if (nn < NN) {
            q[(size_t)nn * HC + t] = qr;
            k[(size_t)nn * HC + t] = F2B(ak[i] + bkv);
            v[(size_t)nn * HC + t] = F2B(av[i] + bvv);
        }
    }
    __syncthreads();
    int h2 = t >> 6;
    float accq[NPB];
#pragma unroll
    for (int i = 0; i < NPB; ++i) accq[i] = 0.f;
    for (int c = 0; c < HID; ++c) {
        float wt = WeT[(size_t)c * HC + t];
#pragma unroll
        for (int i = 0; i < NPB; ++i) accq[i] += qs[i][h2 * 64 + c] * wt;
    }
    for (int i = 0; i < NPB; ++i) {
        int nn = n0 + i;
        if (nn < NN) qe[(size_t)nn * HC + t] = accq[i];
    }
}

// ---------------- FUSED attn: alpha + online softmax + aggregate + proj + skip + LN ----------------
__global__ void gt_attn_fused(const float* __restrict__ q, const float* __restrict__ qe,
                              const bf16* __restrict__ k, const bf16* __restrict__ v,
                              const bf16* __restrict__ ef, const float* __restrict__ We,
                              const int* __restrict__ rp, const int* __restrict__ csr,
                              const int* __restrict__ ei, const float* __restrict__ Wskip,
                              const float* __restrict__ bskip, const float* __restrict__ lng,
                              const float* __restrict__ lnb, float* __restrict__ h) {
    int n = blockIdx.x;
    int t = threadIdx.x;   // 256 = 4 waves; wave == head
    int lane = t & 63, wave = t >> 6;
    __shared__ float sQ[HC];
    __shared__ float sQe[HC];
    __shared__ int sE[ECHUNK];
    __shared__ int sSrc[ECHUNK];
    __shared__ float4 sAl[ECHUNK];
    __shared__ float sS[HC];
    __shared__ float sC[HC];
    __shared__ float res[HID];
    sQ[t] = q[(size_t)n * HC + t];
    sQe[t] = qe[(size_t)n * HC + t];
    if (t < HID) res[t] = h[(size_t)n * HID + t];
    int s0 = clampi(rp[n], 0, NE), s1 = clampi(rp[n + 1], s0, NE);
    float mrun = -1e30f, lrun = 0.f, accv = 0.f, accs = 0.f;
    for (int base = s0; base < s1; base += ECHUNK) {
        int m = min(ECHUNK, s1 - base);
        __syncthreads();  // previous chunk's consumers done before restage
        if (t < m) {
            int e = clampi(csr[base + t], 0, NE - 1);
            sE[t] = e;
            sSrc[t] = clampi(ei[e], 0, NN - 1);
        }
        __syncthreads();
        // raw alpha per edge (one wave per edge, 4 heads at once)
        for (int i = wave; i < m; i += 4) {
            const bf16* kk = &k[(size_t)sSrc[i] * HC];
            float efc = B2F(ef[(size_t)sE[i] * HID + lane]);
            float p0 = sQ[lane] * B2F(kk[lane]) + sQe[lane] * efc;
            float p1 = sQ[64 + lane] * B2F(kk[64 + lane]) + sQe[64 + lane] * efc;
            float p2 = sQ[128 + lane] * B2F(kk[128 + lane]) + sQe[128 + lane] * efc;
            float p3 = sQ[192 + lane] * B2F(kk[192 + lane]) + sQe[192 + lane] * efc;
#pragma unroll
            for (int s = 32; s > 0; s >>= 1) {
                p0 += __shfl_down(p0, s, 64);
                p1 += __shfl_down(p1, s, 64);
                p2 += __shfl_down(p2, s, 64);
                p3 += __shfl_down(p3, s, 64);
            }
            if (lane == 0) {
                float4 r;
                r.x = p0 * 0.125f; r.y = p1 * 0.125f; r.z = p2 * 0.125f; r.w = p3 * 0.125f;
                sAl[i] = r;
            }
        }
        __syncthreads();
        // chunk max for this wave's head
        float cmax = -1e30f;
        for (int i = lane; i < m; i += 64) cmax = fmaxf(cmax, ((const float*)&sAl[i])[wave]);
#pragma unroll
        for (int s = 32; s > 0; s >>= 1) cmax = fmaxf(cmax, __shfl_xor(cmax, s, 64));
        float newm = fmaxf(mrun, cmax);
        float scale = __expf(mrun - newm);  // 0 on first chunk
        accv *= scale; accs *= scale; lrun *= scale;
        mrun = newm;
        // weighted gather-accumulate
#pragma unroll 4
        for (int i = 0; i < m; ++i) {
            float wgt = __expf(((const float*)&sAl[i])[wave] - mrun);
            lrun += wgt;
            accv += wgt * B2F(v[(size_t)sSrc[i] * HC + t]);
            accs += wgt * B2F(ef[(size_t)sE[i] * HID + lane]);
        }
    }
    float inv = (s1 > s0) ? (1.f / lrun) : 0.f;
    sS[t] = accs * inv;
    float accvn = accv * inv;
    __syncthreads();
    float proj = 0.f;
    const float* srow = &sS[wave * 64];
#pragma unroll 8
    for (int j = 0; j < HID; ++j) proj += srow[j] * We[(size_t)j * HC + t];
    sC[t] = accvn + proj;
    __syncthreads();
    if (t < HID) {
        float conv = 0.25f * (sC[t] + sC[HID + t] + sC[2 * HID + t] + sC[3 * HID + t]);
        float sk = bskip[t];
#pragma unroll 8
        for (int j = 0; j < HID; ++j) sk += res[j] * Wskip[j * HID + t];
        float y = conv + sk + res[t];
        float mm = y;
#pragma unroll
        for (int s = 32; s > 0; s >>= 1) mm += __shfl_xor(mm, s, 64);
        mm *= (1.f / HID);
        float d = y - mm;
        float vv = d * d;
#pragma unroll
        for (int s = 32; s > 0; s >>= 1) vv += __shfl_xor(vv, s, 64);
        vv *= (1.f / HID);
        float o = d * rsqrtf(vv + 1e-5f) * lng[t] + lnb[t];
        h[(size_t)n * HID + t] = fmaxf(o, 0.f);
    }
}

// ---------------- pool (true count) + classifier ----------------
__global__ void gt_pool_classify(const float* __restrict__ h, const int* __restrict__ batch,
                                 const float* __restrict__ W, const float* __restrict__ b,
                                 float* __restrict__ out) {
    int g = blockIdx.x;
    int c = threadIdx.x;
    __shared__ float pooled[HID];
    __shared__ float lg[4];
    __shared__ int bounds[2];
    if (c < 2) {
        int target = g + c;
        int lo = 0, hi = NN;
        while (lo < hi) {
            int mid = (lo + hi) >> 1;
            if (batch[mid] < target) lo = mid + 1; else hi = mid;
        }
        bounds[c] = lo;
    }
    __syncthreads();
    int n0 = bounds[0], n1 = bounds[1];
    float s = 0.f;
    for (int n = n0; n < n1; ++n) s += h[(size_t)n * HID + c];
    float divf = fmaxf((float)(n1 - n0), 1.f);
    pooled[c] = s / divf;
    __syncthreads();
    if (c < NCLASSES) {
        float acc = 0.f;
        for (int j = 0; j < HID; ++j) acc += pooled[j] * W[j * NCLASSES + c];
        lg[c] = acc + b[c];
    }
    __syncthreads();
    if (c == 0) {
        float m = fmaxf(lg[0], fmaxf(lg[1], lg[2]));
        float ssum = 0.f;
        for (int cc = 0; cc < NCLASSES; ++cc) ssum += __expf(lg[cc] - m);
        float lse = logf(ssum);
        for (int cc = 0; cc < NCLASSES; ++cc) out[g * NCLASSES + cc] = lg[cc] - m - lse;
    }
}

extern "C" void kernel_launch(void* const* d_in, const int* in_sizes, int n_in,
                              void* d_out, int out_size, void* d_ws, size_t ws_size,
                              hipStream_t stream) {
    float* out = (float*)d_out;

    static const int EXPECT[23] = {2560000, 2048000, 8192, 64, 512, 64, 4096, 64,
                                   49152, 768, 49152, 768, 49152, 768, 49152,
                                   12288, 192, 192, 192, 192, 3, 512000, 20000};
    int bad = -1;
    if (n_in != 23) bad = 99;
    else {
        for (int i = 0; i < 23; ++i) {
            if (in_sizes[i] != EXPECT[i]) { bad = i; break; }
        }
    }
    if (bad >= 0) {
        float val = (bad == 99) ? 4000.f : (5000.f + 10.f * bad);
        gt_write_const<<<1, 256, 0, stream>>>(out, out_size, val);
        return;
    }

    const float* x        = (const float*)d_in[0];
    const float* edge_attr= (const float*)d_in[1];
    const float* node_W   = (const float*)d_in[2];
    const float* node_b   = (const float*)d_in[3];
    const float* e1_W     = (const float*)d_in[4];
    const float* e1_b     = (const float*)d_in[5];
    const float* e2_W     = (const float*)d_in[6];
    const float* e2_b     = (const float*)d_in[7];
    const float* Wq       = (const float*)d_in[8];
    const float* bq       = (const float*)d_in[9];
    const float* Wk       = (const float*)d_in[10];
    const float* bk       = (const float*)d_in[11];
    const float* Wv       = (const float*)d_in[12];
    const float* bv       = (const float*)d_in[13];
    const float* We       = (const float*)d_in[14];
    const float* Wskip    = (const float*)d_in[15];
    const float* bskip    = (const float*)d_in[16];
    const float* lng      = (const float*)d_in[17];
    const float* lnb      = (const float*)d_in[18];
    const float* cls_W    = (const float*)d_in[19];
    const float* cls_b    = (const float*)d_in[20];
    const int*   ei       = (const int*)d_in[21];
    const int*   batch    = (const int*)d_in[22];

    char* w = (char*)d_ws;
    auto alloc = [&](size_t bytes) -> char* {
        char* p = w;
        w += (bytes + 255) & ~(size_t)255;
        return p;
    };
    float* h     = (float*)alloc((size_t)NN * HID * 4);
    bf16*  ef    = (bf16*)alloc((size_t)NE * HID * 2);
    float* q     = (float*)alloc((size_t)NN * HC * 4);
    bf16*  k     = (bf16*)alloc((size_t)NN * HC * 2);
    bf16*  v     = (bf16*)alloc((size_t)NN * HC * 2);
    float* qe    = (float*)alloc((size_t)NN * HC * 4);
    float* WeT   = (float*)alloc((size_t)NLAYERS * HID * HC * 4);
    int*   cnt   = (int*)alloc((size_t)NN * 4);
    int*   rp    = (int*)alloc((size_t)(NN + 1) * 4);
    int*   cur   = (int*)alloc((size_t)NN * 4);
    int*   csr   = (int*)alloc((size_t)NE * 4);

    gt_node_proj<<<(NN + 3) / 4, 256, 0, stream>>>(x, node_W, node_b, h);
    gt_edge_mlp<<<NE / EB, 256, 0, stream>>>(edge_attr, e1_W, e1_b, e2_W, e2_b, ef);
    gt_transpose_we<<<(NLAYERS * HID * HC + 255) / 256, 256, 0, stream>>>(We, WeT);
    gt_zero_i32<<<(NN + 255) / 256, 256, 0, stream>>>(cnt, NN);
    gt_count_dst<<<(NE + 255) / 256, 256, 0, stream>>>(ei, cnt);
    gt_scan_csr<<<1, 256, 0, stream>>>(cnt, rp, cur);
    gt_fill_csr<<<(NE + 255) / 256, 256, 0, stream>>>(ei, cur, csr);

    for (int l = 0; l < NLAYERS; ++l) {
        const float* Wq_l = Wq + (size_t)l * HID * HC;
        const float* bq_l = bq + (size_t)l * HC;
        const float* Wk_l = Wk + (size_t)l * HID * HC;
        const float* bk_l = bk + (size_t)l * HC;
        const float* Wv_l = Wv + (size_t)l * HID * HC;
        const float* bv_l = bv + (size_t)l * HC;
        const float* We_l = We + (size_t)l * HID * HC;
        const float* WeT_l= WeT + (size_t)l * HID * HC;
        const float* Ws_l = Wskip + (size_t)l * HID * HID;
        const float* bs_l = bskip + (size_t)l * HID;
        const float* lg_l = lng + (size_t)l * HID;
        const float* lb_l = lnb + (size_t)l * HID;

        gt_qkv_qe<<<(NN + NPB - 1) / NPB, 256, 0, stream>>>(h, Wq_l, bq_l, Wk_l, bk_l, Wv_l, bv_l,
                                                            WeT_l, q, k, v, qe);
        gt_attn_fused<<<NN, 256, 0, stream>>>(q, qe, k, v, ef, We_l, rp, csr, ei, Ws_l, bs_l,
                                              lg_l, lb_l, h);
    }

    gt_pool_classify<<<NGRAPHS, HID, 0, stream>>>(h, batch, cls_W, cls_b, out);
}